// Round 10
// baseline (262.942 us; speedup 1.0000x reference)
//
#include <hip/hip_runtime.h>
#include <math.h>

#define RAD 20
#define KLEN 41
#define NH 1024
#define NW 2048
#define NHW (NH * NW)

// ---- Compile-time Gaussian-derivative weights (fp64, matches numpy) ----
struct KW { float w[KLEN]; };
constexpr double cexp_neg(double u) {  // exp(-u), 0 <= u <= 0.5
  double term = 1.0, sum = 1.0;
  for (int k = 1; k < 30; ++k) { term *= (-u) / (double)k; sum += term; }
  return sum;
}
constexpr KW make_kw() {
  KW r{};
  double ph[KLEN] = {};
  double s = 0.0;
  for (int i = 0; i < KLEN; ++i) {
    double d = (double)(i - RAD);
    double e = cexp_neg(d * d / 800.0);
    e = e * e; e = e * e; e = e * e; e = e * e;  // ^16
    ph[i] = e; s += e;
  }
  for (int i = 0; i < KLEN; ++i) {
    double d = (double)(i - RAD);
    r.w[i] = (float)((-d / 25.0) * (ph[i] / s) / 2.27);
  }
  return r;
}
static constexpr KW KWC = make_kw();

// Tap-major conv core, 8-accumulator form.
template <int K>
__device__ __forceinline__ void tap(float s, float& r0, float& r1, float& r2,
                                    float& r3, float& r4, float& r5, float& r6,
                                    float& r7) {
  if constexpr (K - 0 >= 0 && K - 0 <= 40) r0 = fmaf(s, KWC.w[K - 0], r0);
  if constexpr (K - 1 >= 0 && K - 1 <= 40) r1 = fmaf(s, KWC.w[K - 1], r1);
  if constexpr (K - 2 >= 0 && K - 2 <= 40) r2 = fmaf(s, KWC.w[K - 2], r2);
  if constexpr (K - 3 >= 0 && K - 3 <= 40) r3 = fmaf(s, KWC.w[K - 3], r3);
  if constexpr (K - 4 >= 0 && K - 4 <= 40) r4 = fmaf(s, KWC.w[K - 4], r4);
  if constexpr (K - 5 >= 0 && K - 5 <= 40) r5 = fmaf(s, KWC.w[K - 5], r5);
  if constexpr (K - 6 >= 0 && K - 6 <= 40) r6 = fmaf(s, KWC.w[K - 6], r6);
  if constexpr (K - 7 >= 0 && K - 7 <= 40) r7 = fmaf(s, KWC.w[K - 7], r7);
}

#define R8 r0, r1, r2, r3, r4, r5, r6, r7

// m_0 numerator: sum over pixels of ||m||_F (fp32 sqrt, fp64 accumulate).
__global__ __launch_bounds__(256) void k_reduce(const float* __restrict__ y,
                                                double* __restrict__ acc) {
  const int tid = blockIdx.x * blockDim.x + threadIdx.x;
  const int stride = gridDim.x * blockDim.x;
  double local = 0.0;
  for (int q = tid; q < NHW / 4; q += stride) {
    float4 a = ((const float4*)y)[q];
    float4 b = ((const float4*)(y + NHW))[q];
    float4 c = ((const float4*)(y + 2 * (size_t)NHW))[q];
    float4 d = ((const float4*)(y + 3 * (size_t)NHW))[q];
    local += (double)sqrtf(a.x * a.x + b.x * b.x + c.x * c.x + d.x * d.x);
    local += (double)sqrtf(a.y * a.y + b.y * b.y + c.y * c.y + d.y * d.y);
    local += (double)sqrtf(a.z * a.z + b.z * b.z + c.z * c.z + d.z * d.z);
    local += (double)sqrtf(a.w * a.w + b.w * b.w + c.w * c.w + d.w * d.w);
  }
#pragma unroll
  for (int off = 32; off > 0; off >>= 1) local += __shfl_down(local, off, 64);
  __shared__ double smem[4];
  const int lane = threadIdx.x & 63;
  const int wid = threadIdx.x >> 6;
  if (lane == 0) smem[wid] = local;
  __syncthreads();
  if (threadIdx.x == 0) {
    double s = smem[0] + smem[1] + smem[2] + smem[3];
    atomicAdd(acc, s);
  }
}

// diffX with swizzled-LDS scalar reads (addr(x)=x+(x>>6), <=2-way banks on
// every read/write). Writes ws planes 7..13. Near its BW floor (~19us).
__global__ __launch_bounds__(256) void k_dx(const float* __restrict__ y,
                                            const float* __restrict__ v,
                                            float* __restrict__ ws) {
  __shared__ float row[2120];  // 2088 padded floats, swizzle-expanded
  const int t = threadIdx.x;
  const int r = blockIdx.x;
  const int ch = blockIdx.y;  // 0..6 -> y0..y4, v0, v1
  const float* src = (ch < 5) ? (y + (size_t)ch * NHW) : (v + (size_t)(ch - 5) * NHW);
  const float* rp = src + (size_t)r * NW;

#define SWZ(i) ((i) + ((i) >> 6))
#define ST(i, val) { const int ii_ = (i); row[SWZ(ii_)] = (val); }

  const float4* rp4 = (const float4*)rp;
  float4 b0 = rp4[t];
  float4 b1 = rp4[t + 256];
  ST(RAD + 4 * t + 0, b0.x)
  ST(RAD + 4 * t + 1, b0.y)
  ST(RAD + 4 * t + 2, b0.z)
  ST(RAD + 4 * t + 3, b0.w)
  ST(RAD + 4 * (t + 256) + 0, b1.x)
  ST(RAD + 4 * (t + 256) + 1, b1.y)
  ST(RAD + 4 * (t + 256) + 2, b1.z)
  ST(RAD + 4 * (t + 256) + 3, b1.w)
  if (t < RAD) {
    ST(t, rp[RAD - t])                // left reflect (no edge repeat)
    ST(NW + RAD + t, rp[NW - 2 - t])  // right reflect
  }
  __syncthreads();

  const int xb = 8 * t;
  float r0 = 0.f, r1 = 0.f, r2 = 0.f, r3 = 0.f;
  float r4 = 0.f, r5 = 0.f, r6 = 0.f, r7 = 0.f;
#define RD(k) { const int x_ = xb + (k); float s_ = row[SWZ(x_)]; tap<(k)>(s_, R8); }
  RD(0)  RD(1)  RD(2)  RD(3)  RD(4)  RD(5)  RD(6)  RD(7)
  RD(8)  RD(9)  RD(10) RD(11) RD(12) RD(13) RD(14) RD(15)
  RD(16) RD(17) RD(18) RD(19) RD(20) RD(21) RD(22) RD(23)
  RD(24) RD(25) RD(26) RD(27) RD(28) RD(29) RD(30) RD(31)
  RD(32) RD(33) RD(34) RD(35) RD(36) RD(37) RD(38) RD(39)
  RD(40) RD(41) RD(42) RD(43) RD(44) RD(45) RD(46) RD(47)
#undef RD

  float4 o0, o1;
  o0.x = r0; o0.y = r1; o0.z = r2; o0.w = r3;
  o1.x = r4; o1.y = r5; o1.z = r6; o1.w = r7;
  float4* dst = (float4*)(ws + (size_t)(7 + ch) * NHW + (size_t)r * NW + xb);
  dst[0] = o0;
  dst[1] = o1;
}

// ---- Fused diffY + pointwise: barrier-free, LDS-free, direct-global ----
// Each thread owns 8 consecutive y-outputs at one x and reads its 48-row
// window straight from global (row reads are 256B/wave coalesced). Halo
// amplification is 6x but lands in L2: grid (8,128) -> XCD = linear id % 8
// = bx, so each XCD walks a fixed 256-px x-strip in y order (working set
// ~340KB << 4MB L2); L3 (256MB) holds all 7 planes (59MB) as backstop.
// Tap order ascending-k unchanged -> bit-identical dY.
__global__ __launch_bounds__(256, 4) void k_dyf(
    const float* __restrict__ y, const float* __restrict__ v,
    const float* __restrict__ gds, const float* __restrict__ cadc,
    const float* __restrict__ myoc, const float* __restrict__ ws,
    const double* __restrict__ acc, float* __restrict__ out) {
  const int x = blockIdx.x * 256 + threadIdx.x;
  const int yb = blockIdx.y * 8;  // 8 output rows per thread

  const float m0 = (float)(acc[0] / (double)NHW);
  const float cad0 = fmaxf(cadc[0], 0.f);
  const float cad1 = fmaxf(cadc[1], 0.f);
  const float cad2 = fmaxf(cadc[2], 0.f);
  const float my0 = fmaxf(myoc[0], 0.f);
  const float my1 = fmaxf(myoc[1], 0.f);
  const float my2 = fmaxf(myoc[2], 0.f);
  const float my3 = fmaxf(myoc[3], 0.f);
  const float my4 = fmaxf(myoc[4], 0.f);

#define DECL8(P)                                                       \
  float P##0 = 0.f, P##1 = 0.f, P##2 = 0.f, P##3 = 0.f, P##4 = 0.f,    \
        P##5 = 0.f, P##6 = 0.f, P##7 = 0.f;

// One window row: wrap row index is block-uniform (SGPR math), x per-lane.
#define CG(P, k)                                                              \
  {                                                                           \
    float s_ = sp_[(size_t)(((yb - RAD + (k)) + NH) & (NH - 1)) * NW + x];    \
    tap<(k)>(s_, P##0, P##1, P##2, P##3, P##4, P##5, P##6, P##7);             \
  }
#define CONVG(P, srcp)                                                        \
  {                                                                           \
    const float* sp_ = (srcp);                                                \
    CG(P, 0)  CG(P, 1)  CG(P, 2)  CG(P, 3)  CG(P, 4)  CG(P, 5)               \
    CG(P, 6)  CG(P, 7)  CG(P, 8)  CG(P, 9)  CG(P, 10) CG(P, 11)              \
    CG(P, 12) CG(P, 13) CG(P, 14) CG(P, 15) CG(P, 16) CG(P, 17)              \
    CG(P, 18) CG(P, 19) CG(P, 20) CG(P, 21) CG(P, 22) CG(P, 23)              \
    CG(P, 24) CG(P, 25) CG(P, 26) CG(P, 27) CG(P, 28) CG(P, 29)              \
    CG(P, 30) CG(P, 31) CG(P, 32) CG(P, 33) CG(P, 34) CG(P, 35)              \
    CG(P, 36) CG(P, 37) CG(P, 38) CG(P, 39) CG(P, 40) CG(P, 41)              \
    CG(P, 42) CG(P, 43) CG(P, 44) CG(P, 45) CG(P, 46) CG(P, 47)              \
  }

  DECL8(ym00) DECL8(ym01) DECL8(ym10) DECL8(ym11)
  DECL8(yc) DECL8(yv0) DECL8(yv1)

  CONVG(ym00, y)
  CONVG(ym01, y + (size_t)NHW)
  CONVG(ym10, y + 2 * (size_t)NHW)
  CONVG(ym11, y + 3 * (size_t)NHW)
  CONVG(yc, y + 4 * (size_t)NHW)
  CONVG(yv0, v)
  CONVG(yv1, v + (size_t)NHW)

  // Pointwise algebra per owned pixel (rows yb+q, col x). m/c/v re-reads
  // are L2-hot (this thread's conv just fetched those rows).
#define POINT(q)                                                              \
  {                                                                           \
    const size_t idx = (size_t)(yb + (q)) * NW + x;                           \
    const float m00 = y[idx];                                                 \
    const float m01 = y[idx + (size_t)NHW];                                   \
    const float m10 = y[idx + 2 * (size_t)NHW];                               \
    const float m11 = y[idx + 3 * (size_t)NHW];                               \
    const float c = y[idx + 4 * (size_t)NHW];                                 \
    const float v0 = v[idx];                                                  \
    const float v1 = v[idx + (size_t)NHW];                                    \
    const float g = gds[idx];                                                 \
    const float dY_m00 = ym00##q, dY_m01 = ym01##q;                           \
    const float dY_m10 = ym10##q, dY_m11 = ym11##q;                           \
    const float dY_c = yc##q, dY_v0 = yv0##q, dY_v1 = yv1##q;                 \
    const float dX_m00 = ws[idx + 7 * (size_t)NHW];                           \
    const float dX_m01 = ws[idx + 8 * (size_t)NHW];                           \
    const float dX_m10 = ws[idx + 9 * (size_t)NHW];                           \
    const float dX_m11 = ws[idx + 10 * (size_t)NHW];                          \
    const float dX_c = ws[idx + 11 * (size_t)NHW];                            \
    const float dX_v0 = ws[idx + 12 * (size_t)NHW];                           \
    const float dX_v1 = ws[idx + 13 * (size_t)NHW];                           \
    const float gv00 = dY_v0, gv01 = dX_v0, gv10 = dY_v1, gv11 = dX_v1;       \
    const float ww = -0.5f * (gv01 - gv10);                                   \
    const float E00 = gv00, E11 = gv11;                                       \
    const float E01 = 0.5f * (gv01 + gv10);                                   \
    const float E10 = E01;                                                    \
    const float trm = m00 + m11;                                              \
    const float dev00 = m00 - 0.5f * trm;                                     \
    const float dev01 = m01;                                                  \
    const float dev10 = m10;                                                  \
    const float dev11 = m11 - 0.5f * trm;                                     \
    const float dmag_sq =                                                     \
        dev00 * dev00 + dev01 * dev01 + dev10 * dev10 + dev11 * dev11;        \
    const float dm = sqrtf(dmag_sq);                                          \
    const float dm2 = dm * dm;                                                \
    const float devE = dev00 * E00 + dev01 * E01 + dev10 * E10 + dev11 * E11; \
    const float sg = (devE > 0.f) ? 1.f : ((devE < 0.f) ? -1.f : 0.f);        \
    const float coef = sg * devE / dm2;                                       \
    const float sc = 0.5f * dm / m0;                                          \
    const float Ea00 = (E00 - coef * dev00) * sc;                             \
    const float Ea01 = (E01 - coef * dev01) * sc;                             \
    const float Ea10 = (E10 - coef * dev10) * sc;                             \
    const float Ea11 = (E11 - coef * dev11) * sc;                             \
    const float Ep00 = E00 - Ea00;                                            \
    const float Ep01 = E01 - Ea01;                                            \
    const float Ep10 = E10 - Ea10;                                            \
    const float Ep11 = E11 - Ea11;                                            \
    const float mE00 = (m00 * Ep00 + m01 * Ep10) + (Ep00 * m00 + Ep01 * m10); \
    const float mE01 = (m00 * Ep01 + m01 * Ep11) + (Ep00 * m01 + Ep01 * m11); \
    const float mE10 = (m10 * Ep00 + m11 * Ep10) + (Ep10 * m00 + Ep11 * m10); \
    const float mE11 = (m10 * Ep01 + m11 * Ep11) + (Ep10 * m01 + Ep11 * m11); \
    const float divv = gv00 + gv11;                                           \
    const float cdot =                                                        \
        -(v0 * dY_c + v1 * dX_c) - cad0 * c + cad1 * c * divv + cad2 * g;     \
    const float md00 = -(v0 * dY_m00 + v1 * dX_m00) - ww * m10 - ww * m01 -   \
                       my0 * m00 + my1 * mE00 - my2 * c * mE00 + my3 * trm +  \
                       my4 * trm * m00;                                       \
    const float md01 = -(v0 * dY_m01 + v1 * dX_m01) - ww * m11 + ww * m00 -   \
                       my0 * m01 + my1 * mE01 - my2 * c * mE01 +              \
                       my4 * trm * m01;                                       \
    const float md10 = -(v0 * dY_m10 + v1 * dX_m10) + ww * m00 - ww * m11 -   \
                       my0 * m10 + my1 * mE10 - my2 * c * mE10 +              \
                       my4 * trm * m10;                                       \
    const float md11 = -(v0 * dY_m11 + v1 * dX_m11) + ww * m01 + ww * m10 -   \
                       my0 * m11 + my1 * mE11 - my2 * c * mE11 +              \
                       my4 * trm * m11;                                       \
    out[idx] = md00;                                                          \
    out[idx + (size_t)NHW] = md01;                                            \
    out[idx + 2 * (size_t)NHW] = md10;                                        \
    out[idx + 3 * (size_t)NHW] = md11;                                        \
    out[idx + 4 * (size_t)NHW] = cdot;                                        \
  }

  POINT(0) POINT(1) POINT(2) POINT(3)
  POINT(4) POINT(5) POINT(6) POINT(7)
#undef POINT
}

extern "C" void kernel_launch(void* const* d_in, const int* in_sizes, int n_in,
                              void* d_out, int out_size, void* d_ws, size_t ws_size,
                              hipStream_t stream) {
  (void)in_sizes; (void)n_in; (void)out_size; (void)ws_size;
  const float* y = (const float*)d_in[0];
  const float* v = (const float*)d_in[1];
  const float* gds = (const float*)d_in[2];
  const float* cadc = (const float*)d_in[3];
  const float* myoc = (const float*)d_in[4];
  float* out = (float*)d_out;

  double* acc = (double*)d_ws;                       // 8B accumulator
  float* planes = (float*)((char*)d_ws + 512);       // 14 x NHW fp32 planes (7..13 used)

  hipMemsetAsync(acc, 0, sizeof(double), stream);
  k_reduce<<<dim3(1024), dim3(256), 0, stream>>>(y, acc);
  k_dx<<<dim3(NH, 7), dim3(256), 0, stream>>>(y, v, planes);
  k_dyf<<<dim3(NW / 256, NH / 8), dim3(256), 0, stream>>>(y, v, gds, cadc, myoc,
                                                          planes, acc, out);
}

// Round 11
// 255.001 us; speedup vs baseline: 1.0311x; 1.0311x over previous
//
#include <hip/hip_runtime.h>
#include <math.h>

#define RAD 20
#define KLEN 41
#define NH 1024
#define NW 2048
#define NHW (NH * NW)

// ---- Compile-time Gaussian-derivative weights (fp64, matches numpy) ----
struct KW { float w[KLEN]; };
constexpr double cexp_neg(double u) {  // exp(-u), 0 <= u <= 0.5
  double term = 1.0, sum = 1.0;
  for (int k = 1; k < 30; ++k) { term *= (-u) / (double)k; sum += term; }
  return sum;
}
constexpr KW make_kw() {
  KW r{};
  double ph[KLEN] = {};
  double s = 0.0;
  for (int i = 0; i < KLEN; ++i) {
    double d = (double)(i - RAD);
    double e = cexp_neg(d * d / 800.0);
    e = e * e; e = e * e; e = e * e; e = e * e;  // ^16
    ph[i] = e; s += e;
  }
  for (int i = 0; i < KLEN; ++i) {
    double d = (double)(i - RAD);
    r.w[i] = (float)((-d / 25.0) * (ph[i] / s) / 2.27);
  }
  return r;
}
static constexpr KW KWC = make_kw();

// Tap-major conv core, 8-accumulator form.
template <int K>
__device__ __forceinline__ void tap(float s, float& r0, float& r1, float& r2,
                                    float& r3, float& r4, float& r5, float& r6,
                                    float& r7) {
  if constexpr (K - 0 >= 0 && K - 0 <= 40) r0 = fmaf(s, KWC.w[K - 0], r0);
  if constexpr (K - 1 >= 0 && K - 1 <= 40) r1 = fmaf(s, KWC.w[K - 1], r1);
  if constexpr (K - 2 >= 0 && K - 2 <= 40) r2 = fmaf(s, KWC.w[K - 2], r2);
  if constexpr (K - 3 >= 0 && K - 3 <= 40) r3 = fmaf(s, KWC.w[K - 3], r3);
  if constexpr (K - 4 >= 0 && K - 4 <= 40) r4 = fmaf(s, KWC.w[K - 4], r4);
  if constexpr (K - 5 >= 0 && K - 5 <= 40) r5 = fmaf(s, KWC.w[K - 5], r5);
  if constexpr (K - 6 >= 0 && K - 6 <= 40) r6 = fmaf(s, KWC.w[K - 6], r6);
  if constexpr (K - 7 >= 0 && K - 7 <= 40) r7 = fmaf(s, KWC.w[K - 7], r7);
}

#define R8 r0, r1, r2, r3, r4, r5, r6, r7

#define TW 64  // tile width (x)
#define TH 32  // output rows per block
#define TILE_CH ((TH + 2 * RAD) * TW)  // 72*64 = 4608 floats per channel slot

// Column conv along y within a staged channel tile (same chunk/tap order as
// the original k_dy -> bit-identical dY results).
__device__ __forceinline__ void conv_col(const float* __restrict__ t, int base,
                                         int lane, float& r0, float& r1,
                                         float& r2, float& r3, float& r4,
                                         float& r5, float& r6, float& r7) {
#define CCHUNK(c)                                      \
  {                                                    \
    float s0 = t[(base + 4 * (c) + 0) * TW + lane];    \
    float s1 = t[(base + 4 * (c) + 1) * TW + lane];    \
    float s2 = t[(base + 4 * (c) + 2) * TW + lane];    \
    float s3 = t[(base + 4 * (c) + 3) * TW + lane];    \
    tap<4 * (c) + 0>(s0, R8);                          \
    tap<4 * (c) + 1>(s1, R8);                          \
    tap<4 * (c) + 2>(s2, R8);                          \
    tap<4 * (c) + 3>(s3, R8);                          \
  }
  CCHUNK(0) CCHUNK(1) CCHUNK(2) CCHUNK(3) CCHUNK(4) CCHUNK(5)
  CCHUNK(6) CCHUNK(7) CCHUNK(8) CCHUNK(9) CCHUNK(10) CCHUNK(11)
#undef CCHUNK
}

// diffX with swizzled-LDS scalar reads (addr(x)=x+(x>>6), <=2-way banks).
// Writes ws planes 7..13. ch==0 blocks additionally compute this row's
// contribution to sum ||m||_F (planes 1-3 rows are L3-hot: they are read
// by their own ch-blocks too), replacing the former k_reduce dispatch.
__global__ __launch_bounds__(256) void k_dx(const float* __restrict__ y,
                                            const float* __restrict__ v,
                                            float* __restrict__ ws,
                                            double* __restrict__ acc) {
  __shared__ float row[2120];  // 2088 padded floats, swizzle-expanded
  __shared__ double rsm[4];
  const int t = threadIdx.x;
  const int r = blockIdx.x;
  const int ch = blockIdx.y;  // 0..6 -> y0..y4, v0, v1
  const float* src = (ch < 5) ? (y + (size_t)ch * NHW) : (v + (size_t)(ch - 5) * NHW);
  const float* rp = src + (size_t)r * NW;

#define SWZ(i) ((i) + ((i) >> 6))
#define ST(i, val) { const int ii_ = (i); row[SWZ(ii_)] = (val); }

  const float4* rp4 = (const float4*)rp;
  float4 b0 = rp4[t];
  float4 b1 = rp4[t + 256];

  // m0-reduction loads (ch0 only): planes 1..3, same row. Issued early so
  // latency overlaps the LDS staging below.
  float4 a1x, a1y, a2x, a2y, a3x, a3y;
  if (ch == 0) {
    const float4* p1 = (const float4*)(y + (size_t)NHW + (size_t)r * NW);
    const float4* p2 = (const float4*)(y + 2 * (size_t)NHW + (size_t)r * NW);
    const float4* p3 = (const float4*)(y + 3 * (size_t)NHW + (size_t)r * NW);
    a1x = p1[t]; a1y = p1[t + 256];
    a2x = p2[t]; a2y = p2[t + 256];
    a3x = p3[t]; a3y = p3[t + 256];
  }

  ST(RAD + 4 * t + 0, b0.x)
  ST(RAD + 4 * t + 1, b0.y)
  ST(RAD + 4 * t + 2, b0.z)
  ST(RAD + 4 * t + 3, b0.w)
  ST(RAD + 4 * (t + 256) + 0, b1.x)
  ST(RAD + 4 * (t + 256) + 1, b1.y)
  ST(RAD + 4 * (t + 256) + 2, b1.z)
  ST(RAD + 4 * (t + 256) + 3, b1.w)
  if (t < RAD) {
    ST(t, rp[RAD - t])                // left reflect (no edge repeat)
    ST(NW + RAD + t, rp[NW - 2 - t])  // right reflect
  }
  __syncthreads();

  const int xb = 8 * t;
  float r0 = 0.f, r1 = 0.f, r2 = 0.f, r3 = 0.f;
  float r4 = 0.f, r5 = 0.f, r6 = 0.f, r7 = 0.f;
#define RD(k) { const int x_ = xb + (k); float s_ = row[SWZ(x_)]; tap<(k)>(s_, R8); }
  RD(0)  RD(1)  RD(2)  RD(3)  RD(4)  RD(5)  RD(6)  RD(7)
  RD(8)  RD(9)  RD(10) RD(11) RD(12) RD(13) RD(14) RD(15)
  RD(16) RD(17) RD(18) RD(19) RD(20) RD(21) RD(22) RD(23)
  RD(24) RD(25) RD(26) RD(27) RD(28) RD(29) RD(30) RD(31)
  RD(32) RD(33) RD(34) RD(35) RD(36) RD(37) RD(38) RD(39)
  RD(40) RD(41) RD(42) RD(43) RD(44) RD(45) RD(46) RD(47)
#undef RD

  float4 o0, o1;
  o0.x = r0; o0.y = r1; o0.z = r2; o0.w = r3;
  o1.x = r4; o1.y = r5; o1.z = r6; o1.w = r7;
  float4* dst = (float4*)(ws + (size_t)(7 + ch) * NHW + (size_t)r * NW + xb);
  dst[0] = o0;
  dst[1] = o1;

  if (ch == 0) {  // block-uniform branch
    double local =
        (double)sqrtf(b0.x * b0.x + a1x.x * a1x.x + a2x.x * a2x.x + a3x.x * a3x.x) +
        (double)sqrtf(b0.y * b0.y + a1x.y * a1x.y + a2x.y * a2x.y + a3x.y * a3x.y) +
        (double)sqrtf(b0.z * b0.z + a1x.z * a1x.z + a2x.z * a2x.z + a3x.z * a3x.z) +
        (double)sqrtf(b0.w * b0.w + a1x.w * a1x.w + a2x.w * a2x.w + a3x.w * a3x.w) +
        (double)sqrtf(b1.x * b1.x + a1y.x * a1y.x + a2y.x * a2y.x + a3y.x * a3y.x) +
        (double)sqrtf(b1.y * b1.y + a1y.y * a1y.y + a2y.y * a2y.y + a3y.y * a3y.y) +
        (double)sqrtf(b1.z * b1.z + a1y.z * a1y.z + a2y.z * a2y.z + a3y.z * a3y.z) +
        (double)sqrtf(b1.w * b1.w + a1y.w * a1y.w + a2y.w * a2y.w + a3y.w * a3y.w);
#pragma unroll
    for (int off = 32; off > 0; off >>= 1) local += __shfl_down(local, off, 64);
    const int lane = t & 63;
    const int wid = t >> 6;
    if (lane == 0) rsm[wid] = local;
    __syncthreads();
    if (t == 0) atomicAdd(acc, rsm[0] + rsm[1] + rsm[2] + rsm[3]);
  }
}

// ---- Fused diffY + pointwise, 2-slot reg-staged pipeline (round-7 best:
// 44.3us) with float4 staging. Per step: issue next channel's 5 float4
// loads -> conv current slot -> write next slot -> barrier. Slot being
// written was last read in step i-1, sealed by that barrier -> race-free.
// Conv chunk/tap order identical -> bit-identical dY.
__global__ __launch_bounds__(256, 4) void k_dyf(
    const float* __restrict__ y, const float* __restrict__ v,
    const float* __restrict__ gds, const float* __restrict__ cadc,
    const float* __restrict__ myoc, const float* __restrict__ ws,
    const double* __restrict__ acc, float* __restrict__ out) {
  __shared__ float tile[2 * TILE_CH];  // 36864 B
  const int lane = threadIdx.x & 63;
  const int wid = threadIdx.x >> 6;  // 0..3
  const int t = threadIdx.x;
  const int x0 = blockIdx.x * TW;
  const int yb = blockIdx.y * TH;
  const int base = wid * 8;

  const float m0 = (float)(acc[0] / (double)NHW);
  const float cad0 = fmaxf(cadc[0], 0.f);
  const float cad1 = fmaxf(cadc[1], 0.f);
  const float cad2 = fmaxf(cadc[2], 0.f);
  const float my0 = fmaxf(myoc[0], 0.f);
  const float my1 = fmaxf(myoc[1], 0.f);
  const float my2 = fmaxf(myoc[2], 0.f);
  const float my3 = fmaxf(myoc[3], 0.f);
  const float my4 = fmaxf(myoc[4], 0.f);

  // Channel tile = 72 rows x 64 cols = 1152 float4. Thread t owns float4
  // linear indices t, t+256, t+512, t+768 (+ t+1024 if t<128).
  float4 f40, f41, f42, f43, f44;
#define LD4Q(dst, q_, sp_)                                                  \
  {                                                                         \
    const int q = (q_);                                                     \
    const int row_ = q >> 4;                                                \
    const int c4_ = (q & 15) * 4;                                           \
    const int wr_ = ((yb - RAD + row_) + NH) & (NH - 1);                    \
    dst = *(const float4*)((sp_) + (size_t)wr_ * NW + x0 + c4_);            \
  }
#define LOADCH(srcp)                                                        \
  {                                                                         \
    const float* sp_ = (srcp);                                              \
    LD4Q(f40, t, sp_) LD4Q(f41, t + 256, sp_) LD4Q(f42, t + 512, sp_)       \
    LD4Q(f43, t + 768, sp_)                                                 \
    if (t < 128) { LD4Q(f44, t + 1024, sp_) }                               \
  }
#define WR4Q(src, q_, g)                                                    \
  {                                                                         \
    const int q = (q_);                                                     \
    const int row_ = q >> 4;                                                \
    const int c4_ = (q & 15) * 4;                                           \
    *(float4*)&tile[(g) * TILE_CH + row_ * TW + c4_] = src;                 \
  }
#define WRITECH(g)                                                          \
  {                                                                         \
    WR4Q(f40, t, g) WR4Q(f41, t + 256, g) WR4Q(f42, t + 512, g)             \
    WR4Q(f43, t + 768, g)                                                   \
    if (t < 128) { WR4Q(f44, t + 1024, g) }                                 \
  }
#define DECL8(P)                                                       \
  float P##0 = 0.f, P##1 = 0.f, P##2 = 0.f, P##3 = 0.f, P##4 = 0.f,    \
        P##5 = 0.f, P##6 = 0.f, P##7 = 0.f;
#define CALLCONV(g, P)                                                  \
  conv_col(&tile[(g) * TILE_CH], base, lane, P##0, P##1, P##2, P##3,    \
           P##4, P##5, P##6, P##7);

  DECL8(ym00) DECL8(ym01) DECL8(ym10) DECL8(ym11)
  DECL8(yc) DECL8(yv0) DECL8(yv1)

  // Prologue: stage ch0 (m00) into slot 0.
  LOADCH(y)
  WRITECH(0)
  __syncthreads();
  // Step 0: load m01; conv m00 (slot0); write m01 -> slot1.
  LOADCH(y + (size_t)NHW)
  CALLCONV(0, ym00)
  WRITECH(1)
  __syncthreads();
  // Step 1: load m10; conv m01 (slot1); write m10 -> slot0.
  LOADCH(y + 2 * (size_t)NHW)
  CALLCONV(1, ym01)
  WRITECH(0)
  __syncthreads();
  // Step 2: load m11; conv m10 (slot0); write m11 -> slot1.
  LOADCH(y + 3 * (size_t)NHW)
  CALLCONV(0, ym10)
  WRITECH(1)
  __syncthreads();
  // Step 3: load c; conv m11 (slot1); write c -> slot0.
  LOADCH(y + 4 * (size_t)NHW)
  CALLCONV(1, ym11)
  WRITECH(0)
  __syncthreads();
  // Step 4: load v0; conv c (slot0); write v0 -> slot1.
  LOADCH(v)
  CALLCONV(0, yc)
  WRITECH(1)
  __syncthreads();
  // Step 5: load v1; conv v0 (slot1); write v1 -> slot0.
  LOADCH(v + (size_t)NHW)
  CALLCONV(1, yv0)
  WRITECH(0)
  __syncthreads();
  // Step 6: conv v1 (slot0). No further staging, no barrier needed.
  CALLCONV(0, yv1)

  // Phase C: pointwise algebra per owned pixel (rows yb+base+q, col x0+lane).
  // m/c/v re-reads are L2-hot (this block staged them just now).
#define POINT(q)                                                              \
  {                                                                           \
    const size_t idx = (size_t)(yb + base + (q)) * NW + x0 + lane;            \
    const float m00 = y[idx];                                                 \
    const float m01 = y[idx + (size_t)NHW];                                   \
    const float m10 = y[idx + 2 * (size_t)NHW];                               \
    const float m11 = y[idx + 3 * (size_t)NHW];                               \
    const float c = y[idx + 4 * (size_t)NHW];                                 \
    const float v0 = v[idx];                                                  \
    const float v1 = v[idx + (size_t)NHW];                                    \
    const float g = gds[idx];                                                 \
    const float dY_m00 = ym00##q, dY_m01 = ym01##q;                           \
    const float dY_m10 = ym10##q, dY_m11 = ym11##q;                           \
    const float dY_c = yc##q, dY_v0 = yv0##q, dY_v1 = yv1##q;                 \
    const float dX_m00 = ws[idx + 7 * (size_t)NHW];                           \
    const float dX_m01 = ws[idx + 8 * (size_t)NHW];                           \
    const float dX_m10 = ws[idx + 9 * (size_t)NHW];                           \
    const float dX_m11 = ws[idx + 10 * (size_t)NHW];                          \
    const float dX_c = ws[idx + 11 * (size_t)NHW];                            \
    const float dX_v0 = ws[idx + 12 * (size_t)NHW];                           \
    const float dX_v1 = ws[idx + 13 * (size_t)NHW];                           \
    const float gv00 = dY_v0, gv01 = dX_v0, gv10 = dY_v1, gv11 = dX_v1;       \
    const float ww = -0.5f * (gv01 - gv10);                                   \
    const float E00 = gv00, E11 = gv11;                                       \
    const float E01 = 0.5f * (gv01 + gv10);                                   \
    const float E10 = E01;                                                    \
    const float trm = m00 + m11;                                              \
    const float dev00 = m00 - 0.5f * trm;                                     \
    const float dev01 = m01;                                                  \
    const float dev10 = m10;                                                  \
    const float dev11 = m11 - 0.5f * trm;                                     \
    const float dmag_sq =                                                     \
        dev00 * dev00 + dev01 * dev01 + dev10 * dev10 + dev11 * dev11;        \
    const float dm = sqrtf(dmag_sq);                                          \
    const float dm2 = dm * dm;                                                \
    const float devE = dev00 * E00 + dev01 * E01 + dev10 * E10 + dev11 * E11; \
    const float sg = (devE > 0.f) ? 1.f : ((devE < 0.f) ? -1.f : 0.f);        \
    const float coef = sg * devE / dm2;                                       \
    const float sc = 0.5f * dm / m0;                                          \
    const float Ea00 = (E00 - coef * dev00) * sc;                             \
    const float Ea01 = (E01 - coef * dev01) * sc;                             \
    const float Ea10 = (E10 - coef * dev10) * sc;                             \
    const float Ea11 = (E11 - coef * dev11) * sc;                             \
    const float Ep00 = E00 - Ea00;                                            \
    const float Ep01 = E01 - Ea01;                                            \
    const float Ep10 = E10 - Ea10;                                            \
    const float Ep11 = E11 - Ea11;                                            \
    const float mE00 = (m00 * Ep00 + m01 * Ep10) + (Ep00 * m00 + Ep01 * m10); \
    const float mE01 = (m00 * Ep01 + m01 * Ep11) + (Ep00 * m01 + Ep01 * m11); \
    const float mE10 = (m10 * Ep00 + m11 * Ep10) + (Ep10 * m00 + Ep11 * m10); \
    const float mE11 = (m10 * Ep01 + m11 * Ep11) + (Ep10 * m01 + Ep11 * m11); \
    const float divv = gv00 + gv11;                                           \
    const float cdot =                                                        \
        -(v0 * dY_c + v1 * dX_c) - cad0 * c + cad1 * c * divv + cad2 * g;     \
    const float md00 = -(v0 * dY_m00 + v1 * dX_m00) - ww * m10 - ww * m01 -   \
                       my0 * m00 + my1 * mE00 - my2 * c * mE00 + my3 * trm +  \
                       my4 * trm * m00;                                       \
    const float md01 = -(v0 * dY_m01 + v1 * dX_m01) - ww * m11 + ww * m00 -   \
                       my0 * m01 + my1 * mE01 - my2 * c * mE01 +              \
                       my4 * trm * m01;                                       \
    const float md10 = -(v0 * dY_m10 + v1 * dX_m10) + ww * m00 - ww * m11 -   \
                       my0 * m10 + my1 * mE10 - my2 * c * mE10 +              \
                       my4 * trm * m10;                                       \
    const float md11 = -(v0 * dY_m11 + v1 * dX_m11) + ww * m01 + ww * m10 -   \
                       my0 * m11 + my1 * mE11 - my2 * c * mE11 +              \
                       my4 * trm * m11;                                       \
    out[idx] = md00;                                                          \
    out[idx + (size_t)NHW] = md01;                                            \
    out[idx + 2 * (size_t)NHW] = md10;                                        \
    out[idx + 3 * (size_t)NHW] = md11;                                        \
    out[idx + 4 * (size_t)NHW] = cdot;                                        \
  }

  POINT(0) POINT(1) POINT(2) POINT(3)
  POINT(4) POINT(5) POINT(6) POINT(7)
#undef POINT
}

extern "C" void kernel_launch(void* const* d_in, const int* in_sizes, int n_in,
                              void* d_out, int out_size, void* d_ws, size_t ws_size,
                              hipStream_t stream) {
  (void)in_sizes; (void)n_in; (void)out_size; (void)ws_size;
  const float* y = (const float*)d_in[0];
  const float* v = (const float*)d_in[1];
  const float* gds = (const float*)d_in[2];
  const float* cadc = (const float*)d_in[3];
  const float* myoc = (const float*)d_in[4];
  float* out = (float*)d_out;

  double* acc = (double*)d_ws;                       // 8B accumulator
  float* planes = (float*)((char*)d_ws + 512);       // 14 x NHW fp32 planes (7..13 used)

  hipMemsetAsync(acc, 0, sizeof(double), stream);
  k_dx<<<dim3(NH, 7), dim3(256), 0, stream>>>(y, v, planes, acc);
  k_dyf<<<dim3(NW / TW, NH / TH), dim3(256), 0, stream>>>(y, v, gds, cadc, myoc,
                                                          planes, acc, out);
}

// Round 12
// 174.757 us; speedup vs baseline: 1.5046x; 1.4592x over previous
//
#include <hip/hip_runtime.h>
#include <math.h>

#define RAD 20
#define KLEN 41
#define NH 1024
#define NW 2048
#define NHW (NH * NW)

// ---- Compile-time Gaussian-derivative weights (fp64, matches numpy) ----
struct KW { float w[KLEN]; };
constexpr double cexp_neg(double u) {  // exp(-u), 0 <= u <= 0.5
  double term = 1.0, sum = 1.0;
  for (int k = 1; k < 30; ++k) { term *= (-u) / (double)k; sum += term; }
  return sum;
}
constexpr KW make_kw() {
  KW r{};
  double ph[KLEN] = {};
  double s = 0.0;
  for (int i = 0; i < KLEN; ++i) {
    double d = (double)(i - RAD);
    double e = cexp_neg(d * d / 800.0);
    e = e * e; e = e * e; e = e * e; e = e * e;  // ^16
    ph[i] = e; s += e;
  }
  for (int i = 0; i < KLEN; ++i) {
    double d = (double)(i - RAD);
    r.w[i] = (float)((-d / 25.0) * (ph[i] / s) / 2.27);
  }
  return r;
}
static constexpr KW KWC = make_kw();

// Tap-major conv core, 8-accumulator form.
template <int K>
__device__ __forceinline__ void tap(float s, float& r0, float& r1, float& r2,
                                    float& r3, float& r4, float& r5, float& r6,
                                    float& r7) {
  if constexpr (K - 0 >= 0 && K - 0 <= 40) r0 = fmaf(s, KWC.w[K - 0], r0);
  if constexpr (K - 1 >= 0 && K - 1 <= 40) r1 = fmaf(s, KWC.w[K - 1], r1);
  if constexpr (K - 2 >= 0 && K - 2 <= 40) r2 = fmaf(s, KWC.w[K - 2], r2);
  if constexpr (K - 3 >= 0 && K - 3 <= 40) r3 = fmaf(s, KWC.w[K - 3], r3);
  if constexpr (K - 4 >= 0 && K - 4 <= 40) r4 = fmaf(s, KWC.w[K - 4], r4);
  if constexpr (K - 5 >= 0 && K - 5 <= 40) r5 = fmaf(s, KWC.w[K - 5], r5);
  if constexpr (K - 6 >= 0 && K - 6 <= 40) r6 = fmaf(s, KWC.w[K - 6], r6);
  if constexpr (K - 7 >= 0 && K - 7 <= 40) r7 = fmaf(s, KWC.w[K - 7], r7);
}

#define R8 r0, r1, r2, r3, r4, r5, r6, r7

#define TW 64  // tile width (x)
#define TH 32  // output rows per block
#define TILE_CH ((TH + 2 * RAD) * TW)  // 72*64 = 4608 floats per channel slot

// Column conv along y within a staged channel tile (same chunk/tap order as
// the original k_dy -> bit-identical dY results).
__device__ __forceinline__ void conv_col(const float* __restrict__ t, int base,
                                         int lane, float& r0, float& r1,
                                         float& r2, float& r3, float& r4,
                                         float& r5, float& r6, float& r7) {
#define CCHUNK(c)                                      \
  {                                                    \
    float s0 = t[(base + 4 * (c) + 0) * TW + lane];    \
    float s1 = t[(base + 4 * (c) + 1) * TW + lane];    \
    float s2 = t[(base + 4 * (c) + 2) * TW + lane];    \
    float s3 = t[(base + 4 * (c) + 3) * TW + lane];    \
    tap<4 * (c) + 0>(s0, R8);                          \
    tap<4 * (c) + 1>(s1, R8);                          \
    tap<4 * (c) + 2>(s2, R8);                          \
    tap<4 * (c) + 3>(s3, R8);                          \
  }
  CCHUNK(0) CCHUNK(1) CCHUNK(2) CCHUNK(3) CCHUNK(4) CCHUNK(5)
  CCHUNK(6) CCHUNK(7) CCHUNK(8) CCHUNK(9) CCHUNK(10) CCHUNK(11)
#undef CCHUNK
}

// diffX with swizzled-LDS scalar reads (addr(x)=x+(x>>6), <=2-way banks).
// Writes ws planes 7..13. ch==0 blocks additionally compute this row's
// contribution to sum ||m||_F, replacing the former k_reduce dispatch
// (verified round 11: absmax unchanged, k_dx stayed out of top-5).
__global__ __launch_bounds__(256) void k_dx(const float* __restrict__ y,
                                            const float* __restrict__ v,
                                            float* __restrict__ ws,
                                            double* __restrict__ acc) {
  __shared__ float row[2120];  // 2088 padded floats, swizzle-expanded
  __shared__ double rsm[4];
  const int t = threadIdx.x;
  const int r = blockIdx.x;
  const int ch = blockIdx.y;  // 0..6 -> y0..y4, v0, v1
  const float* src = (ch < 5) ? (y + (size_t)ch * NHW) : (v + (size_t)(ch - 5) * NHW);
  const float* rp = src + (size_t)r * NW;

#define SWZ(i) ((i) + ((i) >> 6))
#define ST(i, val) { const int ii_ = (i); row[SWZ(ii_)] = (val); }

  const float4* rp4 = (const float4*)rp;
  float4 b0 = rp4[t];
  float4 b1 = rp4[t + 256];

  // m0-reduction loads (ch0 only): planes 1..3, same row. Issued early so
  // latency overlaps the LDS staging below.
  float4 a1x, a1y, a2x, a2y, a3x, a3y;
  if (ch == 0) {
    const float4* p1 = (const float4*)(y + (size_t)NHW + (size_t)r * NW);
    const float4* p2 = (const float4*)(y + 2 * (size_t)NHW + (size_t)r * NW);
    const float4* p3 = (const float4*)(y + 3 * (size_t)NHW + (size_t)r * NW);
    a1x = p1[t]; a1y = p1[t + 256];
    a2x = p2[t]; a2y = p2[t + 256];
    a3x = p3[t]; a3y = p3[t + 256];
  }

  ST(RAD + 4 * t + 0, b0.x)
  ST(RAD + 4 * t + 1, b0.y)
  ST(RAD + 4 * t + 2, b0.z)
  ST(RAD + 4 * t + 3, b0.w)
  ST(RAD + 4 * (t + 256) + 0, b1.x)
  ST(RAD + 4 * (t + 256) + 1, b1.y)
  ST(RAD + 4 * (t + 256) + 2, b1.z)
  ST(RAD + 4 * (t + 256) + 3, b1.w)
  if (t < RAD) {
    ST(t, rp[RAD - t])                // left reflect (no edge repeat)
    ST(NW + RAD + t, rp[NW - 2 - t])  // right reflect
  }
  __syncthreads();

  const int xb = 8 * t;
  float r0 = 0.f, r1 = 0.f, r2 = 0.f, r3 = 0.f;
  float r4 = 0.f, r5 = 0.f, r6 = 0.f, r7 = 0.f;
#define RD(k) { const int x_ = xb + (k); float s_ = row[SWZ(x_)]; tap<(k)>(s_, R8); }
  RD(0)  RD(1)  RD(2)  RD(3)  RD(4)  RD(5)  RD(6)  RD(7)
  RD(8)  RD(9)  RD(10) RD(11) RD(12) RD(13) RD(14) RD(15)
  RD(16) RD(17) RD(18) RD(19) RD(20) RD(21) RD(22) RD(23)
  RD(24) RD(25) RD(26) RD(27) RD(28) RD(29) RD(30) RD(31)
  RD(32) RD(33) RD(34) RD(35) RD(36) RD(37) RD(38) RD(39)
  RD(40) RD(41) RD(42) RD(43) RD(44) RD(45) RD(46) RD(47)
#undef RD

  float4 o0, o1;
  o0.x = r0; o0.y = r1; o0.z = r2; o0.w = r3;
  o1.x = r4; o1.y = r5; o1.z = r6; o1.w = r7;
  float4* dst = (float4*)(ws + (size_t)(7 + ch) * NHW + (size_t)r * NW + xb);
  dst[0] = o0;
  dst[1] = o1;

  if (ch == 0) {  // block-uniform branch
    double local =
        (double)sqrtf(b0.x * b0.x + a1x.x * a1x.x + a2x.x * a2x.x + a3x.x * a3x.x) +
        (double)sqrtf(b0.y * b0.y + a1x.y * a1x.y + a2x.y * a2x.y + a3x.y * a3x.y) +
        (double)sqrtf(b0.z * b0.z + a1x.z * a1x.z + a2x.z * a2x.z + a3x.z * a3x.z) +
        (double)sqrtf(b0.w * b0.w + a1x.w * a1x.w + a2x.w * a2x.w + a3x.w * a3x.w) +
        (double)sqrtf(b1.x * b1.x + a1y.x * a1y.x + a2y.x * a2y.x + a3y.x * a3y.x) +
        (double)sqrtf(b1.y * b1.y + a1y.y * a1y.y + a2y.y * a2y.y + a3y.y * a3y.y) +
        (double)sqrtf(b1.z * b1.z + a1y.z * a1y.z + a2y.z * a2y.z + a3y.z * a3y.z) +
        (double)sqrtf(b1.w * b1.w + a1y.w * a1y.w + a2y.w * a2y.w + a3y.w * a3y.w);
#pragma unroll
    for (int off = 32; off > 0; off >>= 1) local += __shfl_down(local, off, 64);
    const int lane = t & 63;
    const int wid = t >> 6;
    if (lane == 0) rsm[wid] = local;
    __syncthreads();
    if (t == 0) atomicAdd(acc, rsm[0] + rsm[1] + rsm[2] + rsm[3]);
  }
}

// ---- Fused diffY + pointwise, 2-slot software-pipelined staging ----
// EXACT round-7 structure (measured 44.3us): scalar reg staging u0..u17,
// wave w stages rows w,w+4,...,w+68; one barrier per channel. Round-11
// lesson: float4 staging with conditional f44 spilled the 56 accumulators
// to scratch (WRITE_SIZE 41->234MB) — do NOT restructure this staging.
__global__ __launch_bounds__(256, 4) void k_dyf(
    const float* __restrict__ y, const float* __restrict__ v,
    const float* __restrict__ gds, const float* __restrict__ cadc,
    const float* __restrict__ myoc, const float* __restrict__ ws,
    const double* __restrict__ acc, float* __restrict__ out) {
  __shared__ float tile[2 * TILE_CH];  // 36864 B
  const int lane = threadIdx.x & 63;
  const int wid = threadIdx.x >> 6;  // 0..3
  const int x0 = blockIdx.x * TW;
  const int yb = blockIdx.y * TH;
  const int base = wid * 8;

  const float m0 = (float)(acc[0] / (double)NHW);
  const float cad0 = fmaxf(cadc[0], 0.f);
  const float cad1 = fmaxf(cadc[1], 0.f);
  const float cad2 = fmaxf(cadc[2], 0.f);
  const float my0 = fmaxf(myoc[0], 0.f);
  const float my1 = fmaxf(myoc[1], 0.f);
  const float my2 = fmaxf(myoc[2], 0.f);
  const float my3 = fmaxf(myoc[3], 0.f);
  const float my4 = fmaxf(myoc[4], 0.f);

#define SGLD(sp, k) \
  (sp)[(size_t)(((yb - RAD + wid + 4 * (k)) + NH) & (NH - 1)) * NW + x0 + lane]

  float u0, u1, u2, u3, u4, u5, u6, u7, u8;
  float u9, u10, u11, u12, u13, u14, u15, u16, u17;

#define LOADCH(srcp)                                                   \
  {                                                                    \
    const float* sp_ = (srcp);                                         \
    u0 = SGLD(sp_, 0); u1 = SGLD(sp_, 1); u2 = SGLD(sp_, 2);           \
    u3 = SGLD(sp_, 3); u4 = SGLD(sp_, 4); u5 = SGLD(sp_, 5);           \
    u6 = SGLD(sp_, 6); u7 = SGLD(sp_, 7); u8 = SGLD(sp_, 8);           \
    u9 = SGLD(sp_, 9); u10 = SGLD(sp_, 10); u11 = SGLD(sp_, 11);       \
    u12 = SGLD(sp_, 12); u13 = SGLD(sp_, 13); u14 = SGLD(sp_, 14);     \
    u15 = SGLD(sp_, 15); u16 = SGLD(sp_, 16); u17 = SGLD(sp_, 17);     \
  }
#define WRITECH(g)                                                        \
  {                                                                       \
    float* tb_ = &tile[(g) * TILE_CH];                                    \
    tb_[(wid + 0) * TW + lane] = u0;   tb_[(wid + 4) * TW + lane] = u1;   \
    tb_[(wid + 8) * TW + lane] = u2;   tb_[(wid + 12) * TW + lane] = u3;  \
    tb_[(wid + 16) * TW + lane] = u4;  tb_[(wid + 20) * TW + lane] = u5;  \
    tb_[(wid + 24) * TW + lane] = u6;  tb_[(wid + 28) * TW + lane] = u7;  \
    tb_[(wid + 32) * TW + lane] = u8;  tb_[(wid + 36) * TW + lane] = u9;  \
    tb_[(wid + 40) * TW + lane] = u10; tb_[(wid + 44) * TW + lane] = u11; \
    tb_[(wid + 48) * TW + lane] = u12; tb_[(wid + 52) * TW + lane] = u13; \
    tb_[(wid + 56) * TW + lane] = u14; tb_[(wid + 60) * TW + lane] = u15; \
    tb_[(wid + 64) * TW + lane] = u16; tb_[(wid + 68) * TW + lane] = u17; \
  }
#define DECL8(P)                                                       \
  float P##0 = 0.f, P##1 = 0.f, P##2 = 0.f, P##3 = 0.f, P##4 = 0.f,    \
        P##5 = 0.f, P##6 = 0.f, P##7 = 0.f;
#define CALLCONV(g, P)                                                  \
  conv_col(&tile[(g) * TILE_CH], base, lane, P##0, P##1, P##2, P##3,    \
           P##4, P##5, P##6, P##7);

  DECL8(ym00) DECL8(ym01) DECL8(ym10) DECL8(ym11)
  DECL8(yc) DECL8(yv0) DECL8(yv1)

  // Prologue: stage ch0 (m00) into slot 0.
  LOADCH(y)
  WRITECH(0)
  __syncthreads();
  // Step 0: conv m00 (slot0); prefetch+write m01 -> slot1.
  LOADCH(y + (size_t)NHW)
  CALLCONV(0, ym00)
  WRITECH(1)
  __syncthreads();
  // Step 1: conv m01 (slot1); prefetch+write m10 -> slot0.
  LOADCH(y + 2 * (size_t)NHW)
  CALLCONV(1, ym01)
  WRITECH(0)
  __syncthreads();
  // Step 2: conv m10 (slot0); prefetch+write m11 -> slot1.
  LOADCH(y + 3 * (size_t)NHW)
  CALLCONV(0, ym10)
  WRITECH(1)
  __syncthreads();
  // Step 3: conv m11 (slot1); prefetch+write c -> slot0.
  LOADCH(y + 4 * (size_t)NHW)
  CALLCONV(1, ym11)
  WRITECH(0)
  __syncthreads();
  // Step 4: conv c (slot0); prefetch+write v0 -> slot1.
  LOADCH(v)
  CALLCONV(0, yc)
  WRITECH(1)
  __syncthreads();
  // Step 5: conv v0 (slot1); prefetch+write v1 -> slot0.
  LOADCH(v + (size_t)NHW)
  CALLCONV(1, yv0)
  WRITECH(0)
  __syncthreads();
  // Step 6: conv v1 (slot0). No further staging, no barrier needed.
  CALLCONV(0, yv1)

  // Phase C: pointwise algebra per owned pixel (rows yb+base+q, col x0+lane).
  // m/c/v re-read from global: L2-hot (this block staged them just now).
#define POINT(q)                                                              \
  {                                                                           \
    const size_t idx = (size_t)(yb + base + (q)) * NW + x0 + lane;            \
    const float m00 = y[idx];                                                 \
    const float m01 = y[idx + (size_t)NHW];                                   \
    const float m10 = y[idx + 2 * (size_t)NHW];                               \
    const float m11 = y[idx + 3 * (size_t)NHW];                               \
    const float c = y[idx + 4 * (size_t)NHW];                                 \
    const float v0 = v[idx];                                                  \
    const float v1 = v[idx + (size_t)NHW];                                    \
    const float g = gds[idx];                                                 \
    const float dY_m00 = ym00##q, dY_m01 = ym01##q;                           \
    const float dY_m10 = ym10##q, dY_m11 = ym11##q;                           \
    const float dY_c = yc##q, dY_v0 = yv0##q, dY_v1 = yv1##q;                 \
    const float dX_m00 = ws[idx + 7 * (size_t)NHW];                           \
    const float dX_m01 = ws[idx + 8 * (size_t)NHW];                           \
    const float dX_m10 = ws[idx + 9 * (size_t)NHW];                           \
    const float dX_m11 = ws[idx + 10 * (size_t)NHW];                          \
    const float dX_c = ws[idx + 11 * (size_t)NHW];                            \
    const float dX_v0 = ws[idx + 12 * (size_t)NHW];                           \
    const float dX_v1 = ws[idx + 13 * (size_t)NHW];                           \
    const float gv00 = dY_v0, gv01 = dX_v0, gv10 = dY_v1, gv11 = dX_v1;       \
    const float ww = -0.5f * (gv01 - gv10);                                   \
    const float E00 = gv00, E11 = gv11;                                       \
    const float E01 = 0.5f * (gv01 + gv10);                                   \
    const float E10 = E01;                                                    \
    const float trm = m00 + m11;                                              \
    const float dev00 = m00 - 0.5f * trm;                                     \
    const float dev01 = m01;                                                  \
    const float dev10 = m10;                                                  \
    const float dev11 = m11 - 0.5f * trm;                                     \
    const float dmag_sq =                                                     \
        dev00 * dev00 + dev01 * dev01 + dev10 * dev10 + dev11 * dev11;        \
    const float dm = sqrtf(dmag_sq);                                          \
    const float dm2 = dm * dm;                                                \
    const float devE = dev00 * E00 + dev01 * E01 + dev10 * E10 + dev11 * E11; \
    const float sg = (devE > 0.f) ? 1.f : ((devE < 0.f) ? -1.f : 0.f);        \
    const float coef = sg * devE / dm2;                                       \
    const float sc = 0.5f * dm / m0;                                          \
    const float Ea00 = (E00 - coef * dev00) * sc;                             \
    const float Ea01 = (E01 - coef * dev01) * sc;                             \
    const float Ea10 = (E10 - coef * dev10) * sc;                             \
    const float Ea11 = (E11 - coef * dev11) * sc;                             \
    const float Ep00 = E00 - Ea00;                                            \
    const float Ep01 = E01 - Ea01;                                            \
    const float Ep10 = E10 - Ea10;                                            \
    const float Ep11 = E11 - Ea11;                                            \
    const float mE00 = (m00 * Ep00 + m01 * Ep10) + (Ep00 * m00 + Ep01 * m10); \
    const float mE01 = (m00 * Ep01 + m01 * Ep11) + (Ep00 * m01 + Ep01 * m11); \
    const float mE10 = (m10 * Ep00 + m11 * Ep10) + (Ep10 * m00 + Ep11 * m10); \
    const float mE11 = (m10 * Ep01 + m11 * Ep11) + (Ep10 * m01 + Ep11 * m11); \
    const float divv = gv00 + gv11;                                           \
    const float cdot =                                                        \
        -(v0 * dY_c + v1 * dX_c) - cad0 * c + cad1 * c * divv + cad2 * g;     \
    const float md00 = -(v0 * dY_m00 + v1 * dX_m00) - ww * m10 - ww * m01 -   \
                       my0 * m00 + my1 * mE00 - my2 * c * mE00 + my3 * trm +  \
                       my4 * trm * m00;                                       \
    const float md01 = -(v0 * dY_m01 + v1 * dX_m01) - ww * m11 + ww * m00 -   \
                       my0 * m01 + my1 * mE01 - my2 * c * mE01 +              \
                       my4 * trm * m01;                                       \
    const float md10 = -(v0 * dY_m10 + v1 * dX_m10) + ww * m00 - ww * m11 -   \
                       my0 * m10 + my1 * mE10 - my2 * c * mE10 +              \
                       my4 * trm * m10;                                       \
    const float md11 = -(v0 * dY_m11 + v1 * dX_m11) + ww * m01 + ww * m10 -   \
                       my0 * m11 + my1 * mE11 - my2 * c * mE11 +              \
                       my4 * trm * m11;                                       \
    out[idx] = md00;                                                          \
    out[idx + (size_t)NHW] = md01;                                            \
    out[idx + 2 * (size_t)NHW] = md10;                                        \
    out[idx + 3 * (size_t)NHW] = md11;                                        \
    out[idx + 4 * (size_t)NHW] = cdot;                                        \
  }

  POINT(0) POINT(1) POINT(2) POINT(3)
  POINT(4) POINT(5) POINT(6) POINT(7)
#undef POINT
}

extern "C" void kernel_launch(void* const* d_in, const int* in_sizes, int n_in,
                              void* d_out, int out_size, void* d_ws, size_t ws_size,
                              hipStream_t stream) {
  (void)in_sizes; (void)n_in; (void)out_size; (void)ws_size;
  const float* y = (const float*)d_in[0];
  const float* v = (const float*)d_in[1];
  const float* gds = (const float*)d_in[2];
  const float* cadc = (const float*)d_in[3];
  const float* myoc = (const float*)d_in[4];
  float* out = (float*)d_out;

  double* acc = (double*)d_ws;                       // 8B accumulator
  float* planes = (float*)((char*)d_ws + 512);       // 14 x NHW fp32 planes (7..13 used)

  hipMemsetAsync(acc, 0, sizeof(double), stream);
  k_dx<<<dim3(NH, 7), dim3(256), 0, stream>>>(y, v, planes, acc);
  k_dyf<<<dim3(NW / TW, NH / TH), dim3(256), 0, stream>>>(y, v, gds, cadc, myoc,
                                                          planes, acc, out);
}

// Round 13
// 170.717 us; speedup vs baseline: 1.5402x; 1.0237x over previous
//
#include <hip/hip_runtime.h>
#include <math.h>

#define RAD 20
#define KLEN 41
#define NH 1024
#define NW 2048
#define NHW (NH * NW)

// ---- Compile-time Gaussian-derivative weights (fp64, matches numpy) ----
struct KW { float w[KLEN]; };
constexpr double cexp_neg(double u) {  // exp(-u), 0 <= u <= 0.5
  double term = 1.0, sum = 1.0;
  for (int k = 1; k < 30; ++k) { term *= (-u) / (double)k; sum += term; }
  return sum;
}
constexpr KW make_kw() {
  KW r{};
  double ph[KLEN] = {};
  double s = 0.0;
  for (int i = 0; i < KLEN; ++i) {
    double d = (double)(i - RAD);
    double e = cexp_neg(d * d / 800.0);
    e = e * e; e = e * e; e = e * e; e = e * e;  // ^16
    ph[i] = e; s += e;
  }
  for (int i = 0; i < KLEN; ++i) {
    double d = (double)(i - RAD);
    r.w[i] = (float)((-d / 25.0) * (ph[i] / s) / 2.27);
  }
  return r;
}
static constexpr KW KWC = make_kw();

// Tap-major conv core, 8-accumulator form.
template <int K>
__device__ __forceinline__ void tap(float s, float& r0, float& r1, float& r2,
                                    float& r3, float& r4, float& r5, float& r6,
                                    float& r7) {
  if constexpr (K - 0 >= 0 && K - 0 <= 40) r0 = fmaf(s, KWC.w[K - 0], r0);
  if constexpr (K - 1 >= 0 && K - 1 <= 40) r1 = fmaf(s, KWC.w[K - 1], r1);
  if constexpr (K - 2 >= 0 && K - 2 <= 40) r2 = fmaf(s, KWC.w[K - 2], r2);
  if constexpr (K - 3 >= 0 && K - 3 <= 40) r3 = fmaf(s, KWC.w[K - 3], r3);
  if constexpr (K - 4 >= 0 && K - 4 <= 40) r4 = fmaf(s, KWC.w[K - 4], r4);
  if constexpr (K - 5 >= 0 && K - 5 <= 40) r5 = fmaf(s, KWC.w[K - 5], r5);
  if constexpr (K - 6 >= 0 && K - 6 <= 40) r6 = fmaf(s, KWC.w[K - 6], r6);
  if constexpr (K - 7 >= 0 && K - 7 <= 40) r7 = fmaf(s, KWC.w[K - 7], r7);
}

#define R8 r0, r1, r2, r3, r4, r5, r6, r7

#define TW 64  // tile width (x)
#define TH 32  // output rows per block
#define TILE_CH ((TH + 2 * RAD) * TW)  // 72*64 = 4608 floats per channel slot

// Column conv along y within a staged channel tile (same chunk/tap order as
// the original k_dy -> bit-identical dY results).
__device__ __forceinline__ void conv_col(const float* __restrict__ t, int base,
                                         int lane, float& r0, float& r1,
                                         float& r2, float& r3, float& r4,
                                         float& r5, float& r6, float& r7) {
#define CCHUNK(c)                                      \
  {                                                    \
    float s0 = t[(base + 4 * (c) + 0) * TW + lane];    \
    float s1 = t[(base + 4 * (c) + 1) * TW + lane];    \
    float s2 = t[(base + 4 * (c) + 2) * TW + lane];    \
    float s3 = t[(base + 4 * (c) + 3) * TW + lane];    \
    tap<4 * (c) + 0>(s0, R8);                          \
    tap<4 * (c) + 1>(s1, R8);                          \
    tap<4 * (c) + 2>(s2, R8);                          \
    tap<4 * (c) + 3>(s3, R8);                          \
  }
  CCHUNK(0) CCHUNK(1) CCHUNK(2) CCHUNK(3) CCHUNK(4) CCHUNK(5)
  CCHUNK(6) CCHUNK(7) CCHUNK(8) CCHUNK(9) CCHUNK(10) CCHUNK(11)
#undef CCHUNK
}

// diffX, 4 rows per block (round-13): stage 4 row buffers with 8 upfront
// independent float4 loads/thread, ONE barrier (was 4), then 4 independent
// row-convs -- load latency hides under 4x compute, barrier cost /4.
// Swizzle addr(x)=x+(x>>6): reads <=2-way. Conv read pattern and tap order
// identical to round-12 -> dX bit-identical. ch==0 blocks also accumulate
// sum ||m||_F via L2-hot re-reads (replaces k_reduce; verified round 12).
__global__ __launch_bounds__(256) void k_dx(const float* __restrict__ y,
                                            const float* __restrict__ v,
                                            float* __restrict__ ws,
                                            double* __restrict__ acc) {
  __shared__ float rows[4][2120];
  __shared__ double rsm[4];
  const int t = threadIdx.x;
  const int lane = t & 63;
  const int wid = t >> 6;  // 0..3 -> halo row
  const int rb = blockIdx.x * 4;
  const int ch = blockIdx.y;  // 0..6 -> y0..y4, v0, v1
  const float* src = (ch < 5) ? (y + (size_t)ch * NHW) : (v + (size_t)(ch - 5) * NHW);

  // 8 independent dense loads: rows rb..rb+3, two float4 each.
  const float4* q0 = (const float4*)(src + (size_t)(rb + 0) * NW);
  const float4* q1 = (const float4*)(src + (size_t)(rb + 1) * NW);
  const float4* q2 = (const float4*)(src + (size_t)(rb + 2) * NW);
  const float4* q3 = (const float4*)(src + (size_t)(rb + 3) * NW);
  float4 a0 = q0[t], a1 = q0[t + 256];
  float4 b0 = q1[t], b1 = q1[t + 256];
  float4 c0 = q2[t], c1 = q2[t + 256];
  float4 d0 = q3[t], d1 = q3[t + 256];

#define SWZ(i) ((i) + ((i) >> 6))
#define STR(j, i, val) { const int ii_ = (i); rows[j][SWZ(ii_)] = (val); }

  STR(0, RAD + 4 * t + 0, a0.x) STR(0, RAD + 4 * t + 1, a0.y)
  STR(0, RAD + 4 * t + 2, a0.z) STR(0, RAD + 4 * t + 3, a0.w)
  STR(0, RAD + 4 * (t + 256) + 0, a1.x) STR(0, RAD + 4 * (t + 256) + 1, a1.y)
  STR(0, RAD + 4 * (t + 256) + 2, a1.z) STR(0, RAD + 4 * (t + 256) + 3, a1.w)
  STR(1, RAD + 4 * t + 0, b0.x) STR(1, RAD + 4 * t + 1, b0.y)
  STR(1, RAD + 4 * t + 2, b0.z) STR(1, RAD + 4 * t + 3, b0.w)
  STR(1, RAD + 4 * (t + 256) + 0, b1.x) STR(1, RAD + 4 * (t + 256) + 1, b1.y)
  STR(1, RAD + 4 * (t + 256) + 2, b1.z) STR(1, RAD + 4 * (t + 256) + 3, b1.w)
  STR(2, RAD + 4 * t + 0, c0.x) STR(2, RAD + 4 * t + 1, c0.y)
  STR(2, RAD + 4 * t + 2, c0.z) STR(2, RAD + 4 * t + 3, c0.w)
  STR(2, RAD + 4 * (t + 256) + 0, c1.x) STR(2, RAD + 4 * (t + 256) + 1, c1.y)
  STR(2, RAD + 4 * (t + 256) + 2, c1.z) STR(2, RAD + 4 * (t + 256) + 3, c1.w)
  STR(3, RAD + 4 * t + 0, d0.x) STR(3, RAD + 4 * t + 1, d0.y)
  STR(3, RAD + 4 * t + 2, d0.z) STR(3, RAD + 4 * t + 3, d0.w)
  STR(3, RAD + 4 * (t + 256) + 0, d1.x) STR(3, RAD + 4 * (t + 256) + 1, d1.y)
  STR(3, RAD + 4 * (t + 256) + 2, d1.z) STR(3, RAD + 4 * (t + 256) + 3, d1.w)

  // Halo: wave `wid` reflects row rb+wid. lane<20 -> left, lane 32..51 -> right.
  {
    const float* rpw = src + (size_t)(rb + wid) * NW;
    if (lane < RAD) {
      STR(wid, lane, rpw[RAD - lane])
    } else if (lane >= 32 && lane < 32 + RAD) {
      const int hp = lane - 32;
      STR(wid, NW + RAD + hp, rpw[NW - 2 - hp])
    }
  }
  __syncthreads();

  const int xb = 8 * t;
#define RDJ(j, k) { float s_ = rows[j][SWZ(xb + (k))]; tap<(k)>(s_, R8); }
#define DXROW(j)                                                              \
  {                                                                           \
    float r0 = 0.f, r1 = 0.f, r2 = 0.f, r3 = 0.f;                             \
    float r4 = 0.f, r5 = 0.f, r6 = 0.f, r7 = 0.f;                             \
    RDJ(j, 0)  RDJ(j, 1)  RDJ(j, 2)  RDJ(j, 3)  RDJ(j, 4)  RDJ(j, 5)         \
    RDJ(j, 6)  RDJ(j, 7)  RDJ(j, 8)  RDJ(j, 9)  RDJ(j, 10) RDJ(j, 11)        \
    RDJ(j, 12) RDJ(j, 13) RDJ(j, 14) RDJ(j, 15) RDJ(j, 16) RDJ(j, 17)        \
    RDJ(j, 18) RDJ(j, 19) RDJ(j, 20) RDJ(j, 21) RDJ(j, 22) RDJ(j, 23)        \
    RDJ(j, 24) RDJ(j, 25) RDJ(j, 26) RDJ(j, 27) RDJ(j, 28) RDJ(j, 29)        \
    RDJ(j, 30) RDJ(j, 31) RDJ(j, 32) RDJ(j, 33) RDJ(j, 34) RDJ(j, 35)        \
    RDJ(j, 36) RDJ(j, 37) RDJ(j, 38) RDJ(j, 39) RDJ(j, 40) RDJ(j, 41)        \
    RDJ(j, 42) RDJ(j, 43) RDJ(j, 44) RDJ(j, 45) RDJ(j, 46) RDJ(j, 47)        \
    float4 o0, o1;                                                            \
    o0.x = r0; o0.y = r1; o0.z = r2; o0.w = r3;                               \
    o1.x = r4; o1.y = r5; o1.z = r6; o1.w = r7;                               \
    float4* dst = (float4*)(ws + (size_t)(7 + ch) * NHW +                     \
                            (size_t)(rb + (j)) * NW + xb);                    \
    dst[0] = o0;                                                              \
    dst[1] = o1;                                                              \
  }
  DXROW(0)
  DXROW(1)
  DXROW(2)
  DXROW(3)
#undef DXROW
#undef RDJ

  if (ch == 0) {  // block-uniform: m_0 numerator over rows rb..rb+3, x=8t..8t+7
    double local = 0.0;
#pragma unroll
    for (int j = 0; j < 4; ++j) {
      const size_t ro = (size_t)(rb + j) * NW + xb;
      float4 p0a = *(const float4*)(y + ro);
      float4 p0b = *(const float4*)(y + ro + 4);
      float4 p1a = *(const float4*)(y + (size_t)NHW + ro);
      float4 p1b = *(const float4*)(y + (size_t)NHW + ro + 4);
      float4 p2a = *(const float4*)(y + 2 * (size_t)NHW + ro);
      float4 p2b = *(const float4*)(y + 2 * (size_t)NHW + ro + 4);
      float4 p3a = *(const float4*)(y + 3 * (size_t)NHW + ro);
      float4 p3b = *(const float4*)(y + 3 * (size_t)NHW + ro + 4);
      local += (double)sqrtf(p0a.x * p0a.x + p1a.x * p1a.x + p2a.x * p2a.x + p3a.x * p3a.x);
      local += (double)sqrtf(p0a.y * p0a.y + p1a.y * p1a.y + p2a.y * p2a.y + p3a.y * p3a.y);
      local += (double)sqrtf(p0a.z * p0a.z + p1a.z * p1a.z + p2a.z * p2a.z + p3a.z * p3a.z);
      local += (double)sqrtf(p0a.w * p0a.w + p1a.w * p1a.w + p2a.w * p2a.w + p3a.w * p3a.w);
      local += (double)sqrtf(p0b.x * p0b.x + p1b.x * p1b.x + p2b.x * p2b.x + p3b.x * p3b.x);
      local += (double)sqrtf(p0b.y * p0b.y + p1b.y * p1b.y + p2b.y * p2b.y + p3b.y * p3b.y);
      local += (double)sqrtf(p0b.z * p0b.z + p1b.z * p1b.z + p2b.z * p2b.z + p3b.z * p3b.z);
      local += (double)sqrtf(p0b.w * p0b.w + p1b.w * p1b.w + p2b.w * p2b.w + p3b.w * p3b.w);
    }
#pragma unroll
    for (int off = 32; off > 0; off >>= 1) local += __shfl_down(local, off, 64);
    if (lane == 0) rsm[wid] = local;
    __syncthreads();
    if (t == 0) atomicAdd(acc, rsm[0] + rsm[1] + rsm[2] + rsm[3]);
  }
}

// ---- Fused diffY + pointwise, 2-slot software-pipelined staging ----
// EXACT round-7 structure (measured 44.3us): scalar reg staging u0..u17,
// wave w stages rows w,w+4,...,w+68; one barrier per channel. Round-11
// lesson: float4 staging with conditional f44 spilled the 56 accumulators
// to scratch (WRITE_SIZE 41->234MB) — do NOT restructure this staging.
__global__ __launch_bounds__(256, 4) void k_dyf(
    const float* __restrict__ y, const float* __restrict__ v,
    const float* __restrict__ gds, const float* __restrict__ cadc,
    const float* __restrict__ myoc, const float* __restrict__ ws,
    const double* __restrict__ acc, float* __restrict__ out) {
  __shared__ float tile[2 * TILE_CH];  // 36864 B
  const int lane = threadIdx.x & 63;
  const int wid = threadIdx.x >> 6;  // 0..3
  const int x0 = blockIdx.x * TW;
  const int yb = blockIdx.y * TH;
  const int base = wid * 8;

  const float m0 = (float)(acc[0] / (double)NHW);
  const float cad0 = fmaxf(cadc[0], 0.f);
  const float cad1 = fmaxf(cadc[1], 0.f);
  const float cad2 = fmaxf(cadc[2], 0.f);
  const float my0 = fmaxf(myoc[0], 0.f);
  const float my1 = fmaxf(myoc[1], 0.f);
  const float my2 = fmaxf(myoc[2], 0.f);
  const float my3 = fmaxf(myoc[3], 0.f);
  const float my4 = fmaxf(myoc[4], 0.f);

#define SGLD(sp, k) \
  (sp)[(size_t)(((yb - RAD + wid + 4 * (k)) + NH) & (NH - 1)) * NW + x0 + lane]

  float u0, u1, u2, u3, u4, u5, u6, u7, u8;
  float u9, u10, u11, u12, u13, u14, u15, u16, u17;

#define LOADCH(srcp)                                                   \
  {                                                                    \
    const float* sp_ = (srcp);                                         \
    u0 = SGLD(sp_, 0); u1 = SGLD(sp_, 1); u2 = SGLD(sp_, 2);           \
    u3 = SGLD(sp_, 3); u4 = SGLD(sp_, 4); u5 = SGLD(sp_, 5);           \
    u6 = SGLD(sp_, 6); u7 = SGLD(sp_, 7); u8 = SGLD(sp_, 8);           \
    u9 = SGLD(sp_, 9); u10 = SGLD(sp_, 10); u11 = SGLD(sp_, 11);       \
    u12 = SGLD(sp_, 12); u13 = SGLD(sp_, 13); u14 = SGLD(sp_, 14);     \
    u15 = SGLD(sp_, 15); u16 = SGLD(sp_, 16); u17 = SGLD(sp_, 17);     \
  }
#define WRITECH(g)                                                        \
  {                                                                       \
    float* tb_ = &tile[(g) * TILE_CH];                                    \
    tb_[(wid + 0) * TW + lane] = u0;   tb_[(wid + 4) * TW + lane] = u1;   \
    tb_[(wid + 8) * TW + lane] = u2;   tb_[(wid + 12) * TW + lane] = u3;  \
    tb_[(wid + 16) * TW + lane] = u4;  tb_[(wid + 20) * TW + lane] = u5;  \
    tb_[(wid + 24) * TW + lane] = u6;  tb_[(wid + 28) * TW + lane] = u7;  \
    tb_[(wid + 32) * TW + lane] = u8;  tb_[(wid + 36) * TW + lane] = u9;  \
    tb_[(wid + 40) * TW + lane] = u10; tb_[(wid + 44) * TW + lane] = u11; \
    tb_[(wid + 48) * TW + lane] = u12; tb_[(wid + 52) * TW + lane] = u13; \
    tb_[(wid + 56) * TW + lane] = u14; tb_[(wid + 60) * TW + lane] = u15; \
    tb_[(wid + 64) * TW + lane] = u16; tb_[(wid + 68) * TW + lane] = u17; \
  }
#define DECL8(P)                                                       \
  float P##0 = 0.f, P##1 = 0.f, P##2 = 0.f, P##3 = 0.f, P##4 = 0.f,    \
        P##5 = 0.f, P##6 = 0.f, P##7 = 0.f;
#define CALLCONV(g, P)                                                  \
  conv_col(&tile[(g) * TILE_CH], base, lane, P##0, P##1, P##2, P##3,    \
           P##4, P##5, P##6, P##7);

  DECL8(ym00) DECL8(ym01) DECL8(ym10) DECL8(ym11)
  DECL8(yc) DECL8(yv0) DECL8(yv1)

  // Prologue: stage ch0 (m00) into slot 0.
  LOADCH(y)
  WRITECH(0)
  __syncthreads();
  // Step 0: conv m00 (slot0); prefetch+write m01 -> slot1.
  LOADCH(y + (size_t)NHW)
  CALLCONV(0, ym00)
  WRITECH(1)
  __syncthreads();
  // Step 1: conv m01 (slot1); prefetch+write m10 -> slot0.
  LOADCH(y + 2 * (size_t)NHW)
  CALLCONV(1, ym01)
  WRITECH(0)
  __syncthreads();
  // Step 2: conv m10 (slot0); prefetch+write m11 -> slot1.
  LOADCH(y + 3 * (size_t)NHW)
  CALLCONV(0, ym10)
  WRITECH(1)
  __syncthreads();
  // Step 3: conv m11 (slot1); prefetch+write c -> slot0.
  LOADCH(y + 4 * (size_t)NHW)
  CALLCONV(1, ym11)
  WRITECH(0)
  __syncthreads();
  // Step 4: conv c (slot0); prefetch+write v0 -> slot1.
  LOADCH(v)
  CALLCONV(0, yc)
  WRITECH(1)
  __syncthreads();
  // Step 5: conv v0 (slot1); prefetch+write v1 -> slot0.
  LOADCH(v + (size_t)NHW)
  CALLCONV(1, yv0)
  WRITECH(0)
  __syncthreads();
  // Step 6: conv v1 (slot0). No further staging, no barrier needed.
  CALLCONV(0, yv1)

  // Phase C: pointwise algebra per owned pixel (rows yb+base+q, col x0+lane).
  // m/c/v re-read from global: L2-hot (this block staged them just now).
#define POINT(q)                                                              \
  {                                                                           \
    const size_t idx = (size_t)(yb + base + (q)) * NW + x0 + lane;            \
    const float m00 = y[idx];                                                 \
    const float m01 = y[idx + (size_t)NHW];                                   \
    const float m10 = y[idx + 2 * (size_t)NHW];                               \
    const float m11 = y[idx + 3 * (size_t)NHW];                               \
    const float c = y[idx + 4 * (size_t)NHW];                                 \
    const float v0 = v[idx];                                                  \
    const float v1 = v[idx + (size_t)NHW];                                    \
    const float g = gds[idx];                                                 \
    const float dY_m00 = ym00##q, dY_m01 = ym01##q;                           \
    const float dY_m10 = ym10##q, dY_m11 = ym11##q;                           \
    const float dY_c = yc##q, dY_v0 = yv0##q, dY_v1 = yv1##q;                 \
    const float dX_m00 = ws[idx + 7 * (size_t)NHW];                           \
    const float dX_m01 = ws[idx + 8 * (size_t)NHW];                           \
    const float dX_m10 = ws[idx + 9 * (size_t)NHW];                           \
    const float dX_m11 = ws[idx + 10 * (size_t)NHW];                          \
    const float dX_c = ws[idx + 11 * (size_t)NHW];                            \
    const float dX_v0 = ws[idx + 12 * (size_t)NHW];                           \
    const float dX_v1 = ws[idx + 13 * (size_t)NHW];                           \
    const float gv00 = dY_v0, gv01 = dX_v0, gv10 = dY_v1, gv11 = dX_v1;       \
    const float ww = -0.5f * (gv01 - gv10);                                   \
    const float E00 = gv00, E11 = gv11;                                       \
    const float E01 = 0.5f * (gv01 + gv10);                                   \
    const float E10 = E01;                                                    \
    const float trm = m00 + m11;                                              \
    const float dev00 = m00 - 0.5f * trm;                                     \
    const float dev01 = m01;                                                  \
    const float dev10 = m10;                                                  \
    const float dev11 = m11 - 0.5f * trm;                                     \
    const float dmag_sq =                                                     \
        dev00 * dev00 + dev01 * dev01 + dev10 * dev10 + dev11 * dev11;        \
    const float dm = sqrtf(dmag_sq);                                          \
    const float dm2 = dm * dm;                                                \
    const float devE = dev00 * E00 + dev01 * E01 + dev10 * E10 + dev11 * E11; \
    const float sg = (devE > 0.f) ? 1.f : ((devE < 0.f) ? -1.f : 0.f);        \
    const float coef = sg * devE / dm2;                                       \
    const float sc = 0.5f * dm / m0;                                          \
    const float Ea00 = (E00 - coef * dev00) * sc;                             \
    const float Ea01 = (E01 - coef * dev01) * sc;                             \
    const float Ea10 = (E10 - coef * dev10) * sc;                             \
    const float Ea11 = (E11 - coef * dev11) * sc;                             \
    const float Ep00 = E00 - Ea00;                                            \
    const float Ep01 = E01 - Ea01;                                            \
    const float Ep10 = E10 - Ea10;                                            \
    const float Ep11 = E11 - Ea11;                                            \
    const float mE00 = (m00 * Ep00 + m01 * Ep10) + (Ep00 * m00 + Ep01 * m10); \
    const float mE01 = (m00 * Ep01 + m01 * Ep11) + (Ep00 * m01 + Ep01 * m11); \
    const float mE10 = (m10 * Ep00 + m11 * Ep10) + (Ep10 * m00 + Ep11 * m10); \
    const float mE11 = (m10 * Ep01 + m11 * Ep11) + (Ep10 * m01 + Ep11 * m11); \
    const float divv = gv00 + gv11;                                           \
    const float cdot =                                                        \
        -(v0 * dY_c + v1 * dX_c) - cad0 * c + cad1 * c * divv + cad2 * g;     \
    const float md00 = -(v0 * dY_m00 + v1 * dX_m00) - ww * m10 - ww * m01 -   \
                       my0 * m00 + my1 * mE00 - my2 * c * mE00 + my3 * trm +  \
                       my4 * trm * m00;                                       \
    const float md01 = -(v0 * dY_m01 + v1 * dX_m01) - ww * m11 + ww * m00 -   \
                       my0 * m01 + my1 * mE01 - my2 * c * mE01 +              \
                       my4 * trm * m01;                                       \
    const float md10 = -(v0 * dY_m10 + v1 * dX_m10) + ww * m00 - ww * m11 -   \
                       my0 * m10 + my1 * mE10 - my2 * c * mE10 +              \
                       my4 * trm * m10;                                       \
    const float md11 = -(v0 * dY_m11 + v1 * dX_m11) + ww * m01 + ww * m10 -   \
                       my0 * m11 + my1 * mE11 - my2 * c * mE11 +              \
                       my4 * trm * m11;                                       \
    out[idx] = md00;                                                          \
    out[idx + (size_t)NHW] = md01;                                            \
    out[idx + 2 * (size_t)NHW] = md10;                                        \
    out[idx + 3 * (size_t)NHW] = md11;                                        \
    out[idx + 4 * (size_t)NHW] = cdot;                                        \
  }

  POINT(0) POINT(1) POINT(2) POINT(3)
  POINT(4) POINT(5) POINT(6) POINT(7)
#undef POINT
}

extern "C" void kernel_launch(void* const* d_in, const int* in_sizes, int n_in,
                              void* d_out, int out_size, void* d_ws, size_t ws_size,
                              hipStream_t stream) {
  (void)in_sizes; (void)n_in; (void)out_size; (void)ws_size;
  const float* y = (const float*)d_in[0];
  const float* v = (const float*)d_in[1];
  const float* gds = (const float*)d_in[2];
  const float* cadc = (const float*)d_in[3];
  const float* myoc = (const float*)d_in[4];
  float* out = (float*)d_out;

  double* acc = (double*)d_ws;                       // 8B accumulator
  float* planes = (float*)((char*)d_ws + 512);       // 14 x NHW fp32 planes (7..13 used)

  hipMemsetAsync(acc, 0, sizeof(double), stream);
  k_dx<<<dim3(NH / 4, 7), dim3(256), 0, stream>>>(y, v, planes, acc);
  k_dyf<<<dim3(NW / TW, NH / TH), dim3(256), 0, stream>>>(y, v, gds, cadc, myoc,
                                                          planes, acc, out);
}

// Round 14
// 167.605 us; speedup vs baseline: 1.5688x; 1.0186x over previous
//
#include <hip/hip_runtime.h>
#include <math.h>

#define RAD 20
#define KLEN 41
#define NH 1024
#define NW 2048
#define NHW (NH * NW)

// ---- Compile-time Gaussian-derivative weights (fp64, matches numpy) ----
struct KW { float w[KLEN]; };
constexpr double cexp_neg(double u) {  // exp(-u), 0 <= u <= 0.5
  double term = 1.0, sum = 1.0;
  for (int k = 1; k < 30; ++k) { term *= (-u) / (double)k; sum += term; }
  return sum;
}
constexpr KW make_kw() {
  KW r{};
  double ph[KLEN] = {};
  double s = 0.0;
  for (int i = 0; i < KLEN; ++i) {
    double d = (double)(i - RAD);
    double e = cexp_neg(d * d / 800.0);
    e = e * e; e = e * e; e = e * e; e = e * e;  // ^16
    ph[i] = e; s += e;
  }
  for (int i = 0; i < KLEN; ++i) {
    double d = (double)(i - RAD);
    r.w[i] = (float)((-d / 25.0) * (ph[i] / s) / 2.27);
  }
  return r;
}
static constexpr KW KWC = make_kw();

// Tap-major conv core, 8-accumulator form.
template <int K>
__device__ __forceinline__ void tap(float s, float& r0, float& r1, float& r2,
                                    float& r3, float& r4, float& r5, float& r6,
                                    float& r7) {
  if constexpr (K - 0 >= 0 && K - 0 <= 40) r0 = fmaf(s, KWC.w[K - 0], r0);
  if constexpr (K - 1 >= 0 && K - 1 <= 40) r1 = fmaf(s, KWC.w[K - 1], r1);
  if constexpr (K - 2 >= 0 && K - 2 <= 40) r2 = fmaf(s, KWC.w[K - 2], r2);
  if constexpr (K - 3 >= 0 && K - 3 <= 40) r3 = fmaf(s, KWC.w[K - 3], r3);
  if constexpr (K - 4 >= 0 && K - 4 <= 40) r4 = fmaf(s, KWC.w[K - 4], r4);
  if constexpr (K - 5 >= 0 && K - 5 <= 40) r5 = fmaf(s, KWC.w[K - 5], r5);
  if constexpr (K - 6 >= 0 && K - 6 <= 40) r6 = fmaf(s, KWC.w[K - 6], r6);
  if constexpr (K - 7 >= 0 && K - 7 <= 40) r7 = fmaf(s, KWC.w[K - 7], r7);
}

#define R8 r0, r1, r2, r3, r4, r5, r6, r7

#define TW 64  // k_dyf tile width (x)
#define TH 64  // k_dyf output rows per block (round-14: was 32)
#define TILE_CH ((TH + 2 * RAD) * TW)  // 104*64 = 6656 floats per channel slot

// Column conv along y within a staged channel tile (same chunk/tap order as
// the original k_dy -> bit-identical dY results).
__device__ __forceinline__ void conv_col(const float* __restrict__ t, int base,
                                         int lane, float& r0, float& r1,
                                         float& r2, float& r3, float& r4,
                                         float& r5, float& r6, float& r7) {
#define CCHUNK(c)                                      \
  {                                                    \
    float s0 = t[(base + 4 * (c) + 0) * TW + lane];    \
    float s1 = t[(base + 4 * (c) + 1) * TW + lane];    \
    float s2 = t[(base + 4 * (c) + 2) * TW + lane];    \
    float s3 = t[(base + 4 * (c) + 3) * TW + lane];    \
    tap<4 * (c) + 0>(s0, R8);                          \
    tap<4 * (c) + 1>(s1, R8);                          \
    tap<4 * (c) + 2>(s2, R8);                          \
    tap<4 * (c) + 3>(s3, R8);                          \
  }
  CCHUNK(0) CCHUNK(1) CCHUNK(2) CCHUNK(3) CCHUNK(4) CCHUNK(5)
  CCHUNK(6) CCHUNK(7) CCHUNK(8) CCHUNK(9) CCHUNK(10) CCHUNK(11)
#undef CCHUNK
}

// diffX, 4 rows per block (round-13 form, measured improvement; unchanged).
__global__ __launch_bounds__(256) void k_dx(const float* __restrict__ y,
                                            const float* __restrict__ v,
                                            float* __restrict__ ws,
                                            double* __restrict__ acc) {
  __shared__ float rows[4][2120];
  __shared__ double rsm[4];
  const int t = threadIdx.x;
  const int lane = t & 63;
  const int wid = t >> 6;  // 0..3 -> halo row
  const int rb = blockIdx.x * 4;
  const int ch = blockIdx.y;  // 0..6 -> y0..y4, v0, v1
  const float* src = (ch < 5) ? (y + (size_t)ch * NHW) : (v + (size_t)(ch - 5) * NHW);

  // 8 independent dense loads: rows rb..rb+3, two float4 each.
  const float4* q0 = (const float4*)(src + (size_t)(rb + 0) * NW);
  const float4* q1 = (const float4*)(src + (size_t)(rb + 1) * NW);
  const float4* q2 = (const float4*)(src + (size_t)(rb + 2) * NW);
  const float4* q3 = (const float4*)(src + (size_t)(rb + 3) * NW);
  float4 a0 = q0[t], a1 = q0[t + 256];
  float4 b0 = q1[t], b1 = q1[t + 256];
  float4 c0 = q2[t], c1 = q2[t + 256];
  float4 d0 = q3[t], d1 = q3[t + 256];

#define SWZ(i) ((i) + ((i) >> 6))
#define STR(j, i, val) { const int ii_ = (i); rows[j][SWZ(ii_)] = (val); }

  STR(0, RAD + 4 * t + 0, a0.x) STR(0, RAD + 4 * t + 1, a0.y)
  STR(0, RAD + 4 * t + 2, a0.z) STR(0, RAD + 4 * t + 3, a0.w)
  STR(0, RAD + 4 * (t + 256) + 0, a1.x) STR(0, RAD + 4 * (t + 256) + 1, a1.y)
  STR(0, RAD + 4 * (t + 256) + 2, a1.z) STR(0, RAD + 4 * (t + 256) + 3, a1.w)
  STR(1, RAD + 4 * t + 0, b0.x) STR(1, RAD + 4 * t + 1, b0.y)
  STR(1, RAD + 4 * t + 2, b0.z) STR(1, RAD + 4 * t + 3, b0.w)
  STR(1, RAD + 4 * (t + 256) + 0, b1.x) STR(1, RAD + 4 * (t + 256) + 1, b1.y)
  STR(1, RAD + 4 * (t + 256) + 2, b1.z) STR(1, RAD + 4 * (t + 256) + 3, b1.w)
  STR(2, RAD + 4 * t + 0, c0.x) STR(2, RAD + 4 * t + 1, c0.y)
  STR(2, RAD + 4 * t + 2, c0.z) STR(2, RAD + 4 * t + 3, c0.w)
  STR(2, RAD + 4 * (t + 256) + 0, c1.x) STR(2, RAD + 4 * (t + 256) + 1, c1.y)
  STR(2, RAD + 4 * (t + 256) + 2, c1.z) STR(2, RAD + 4 * (t + 256) + 3, c1.w)
  STR(3, RAD + 4 * t + 0, d0.x) STR(3, RAD + 4 * t + 1, d0.y)
  STR(3, RAD + 4 * t + 2, d0.z) STR(3, RAD + 4 * t + 3, d0.w)
  STR(3, RAD + 4 * (t + 256) + 0, d1.x) STR(3, RAD + 4 * (t + 256) + 1, d1.y)
  STR(3, RAD + 4 * (t + 256) + 2, d1.z) STR(3, RAD + 4 * (t + 256) + 3, d1.w)

  // Halo: wave `wid` reflects row rb+wid. lane<20 -> left, lane 32..51 -> right.
  {
    const float* rpw = src + (size_t)(rb + wid) * NW;
    if (lane < RAD) {
      STR(wid, lane, rpw[RAD - lane])
    } else if (lane >= 32 && lane < 32 + RAD) {
      const int hp = lane - 32;
      STR(wid, NW + RAD + hp, rpw[NW - 2 - hp])
    }
  }
  __syncthreads();

  const int xb = 8 * t;
#define RDJ(j, k) { float s_ = rows[j][SWZ(xb + (k))]; tap<(k)>(s_, R8); }
#define DXROW(j)                                                              \
  {                                                                           \
    float r0 = 0.f, r1 = 0.f, r2 = 0.f, r3 = 0.f;                             \
    float r4 = 0.f, r5 = 0.f, r6 = 0.f, r7 = 0.f;                             \
    RDJ(j, 0)  RDJ(j, 1)  RDJ(j, 2)  RDJ(j, 3)  RDJ(j, 4)  RDJ(j, 5)         \
    RDJ(j, 6)  RDJ(j, 7)  RDJ(j, 8)  RDJ(j, 9)  RDJ(j, 10) RDJ(j, 11)        \
    RDJ(j, 12) RDJ(j, 13) RDJ(j, 14) RDJ(j, 15) RDJ(j, 16) RDJ(j, 17)        \
    RDJ(j, 18) RDJ(j, 19) RDJ(j, 20) RDJ(j, 21) RDJ(j, 22) RDJ(j, 23)        \
    RDJ(j, 24) RDJ(j, 25) RDJ(j, 26) RDJ(j, 27) RDJ(j, 28) RDJ(j, 29)        \
    RDJ(j, 30) RDJ(j, 31) RDJ(j, 32) RDJ(j, 33) RDJ(j, 34) RDJ(j, 35)        \
    RDJ(j, 36) RDJ(j, 37) RDJ(j, 38) RDJ(j, 39) RDJ(j, 40) RDJ(j, 41)        \
    RDJ(j, 42) RDJ(j, 43) RDJ(j, 44) RDJ(j, 45) RDJ(j, 46) RDJ(j, 47)        \
    float4 o0, o1;                                                            \
    o0.x = r0; o0.y = r1; o0.z = r2; o0.w = r3;                               \
    o1.x = r4; o1.y = r5; o1.z = r6; o1.w = r7;                               \
    float4* dst = (float4*)(ws + (size_t)(7 + ch) * NHW +                     \
                            (size_t)(rb + (j)) * NW + xb);                    \
    dst[0] = o0;                                                              \
    dst[1] = o1;                                                              \
  }
  DXROW(0)
  DXROW(1)
  DXROW(2)
  DXROW(3)
#undef DXROW
#undef RDJ

  if (ch == 0) {  // block-uniform: m_0 numerator over rows rb..rb+3, x=8t..8t+7
    double local = 0.0;
#pragma unroll
    for (int j = 0; j < 4; ++j) {
      const size_t ro = (size_t)(rb + j) * NW + xb;
      float4 p0a = *(const float4*)(y + ro);
      float4 p0b = *(const float4*)(y + ro + 4);
      float4 p1a = *(const float4*)(y + (size_t)NHW + ro);
      float4 p1b = *(const float4*)(y + (size_t)NHW + ro + 4);
      float4 p2a = *(const float4*)(y + 2 * (size_t)NHW + ro);
      float4 p2b = *(const float4*)(y + 2 * (size_t)NHW + ro + 4);
      float4 p3a = *(const float4*)(y + 3 * (size_t)NHW + ro);
      float4 p3b = *(const float4*)(y + 3 * (size_t)NHW + ro + 4);
      local += (double)sqrtf(p0a.x * p0a.x + p1a.x * p1a.x + p2a.x * p2a.x + p3a.x * p3a.x);
      local += (double)sqrtf(p0a.y * p0a.y + p1a.y * p1a.y + p2a.y * p2a.y + p3a.y * p3a.y);
      local += (double)sqrtf(p0a.z * p0a.z + p1a.z * p1a.z + p2a.z * p2a.z + p3a.z * p3a.z);
      local += (double)sqrtf(p0a.w * p0a.w + p1a.w * p1a.w + p2a.w * p2a.w + p3a.w * p3a.w);
      local += (double)sqrtf(p0b.x * p0b.x + p1b.x * p1b.x + p2b.x * p2b.x + p3b.x * p3b.x);
      local += (double)sqrtf(p0b.y * p0b.y + p1b.y * p1b.y + p2b.y * p2b.y + p3b.y * p3b.y);
      local += (double)sqrtf(p0b.z * p0b.z + p1b.z * p1b.z + p2b.z * p2b.z + p3b.z * p3b.z);
      local += (double)sqrtf(p0b.w * p0b.w + p1b.w * p1b.w + p2b.w * p2b.w + p3b.w * p3b.w);
    }
#pragma unroll
    for (int off = 32; off > 0; off >>= 1) local += __shfl_down(local, off, 64);
    if (lane == 0) rsm[wid] = local;
    __syncthreads();
    if (t == 0) atomicAdd(acc, rsm[0] + rsm[1] + rsm[2] + rsm[3]);
  }
}

// ---- Fused diffY + pointwise, 2-slot pipeline, TH=64 (round-14) ----
// 512 threads / 8 waves; tile 104x64 per slot (53.2KB total -> 2 blocks/CU,
// grid 512 = exactly 2/CU, zero tail). Per output row this halves the
// barrier-drain events and cuts staging halo 2.25x -> 1.625x vs TH=32.
// Staging stays the round-7-proven SCALAR named-register pattern (u0..u12)
// -- round-11 lesson: vector/conditional staging spills the 56 accumulators.
// conv_col order unchanged -> dY bit-identical.
__global__ __launch_bounds__(512, 4) void k_dyf(
    const float* __restrict__ y, const float* __restrict__ v,
    const float* __restrict__ gds, const float* __restrict__ cadc,
    const float* __restrict__ myoc, const float* __restrict__ ws,
    const double* __restrict__ acc, float* __restrict__ out) {
  __shared__ float tile[2 * TILE_CH];  // 53248 B
  const int lane = threadIdx.x & 63;
  const int wid = threadIdx.x >> 6;  // 0..7
  const int x0 = blockIdx.x * TW;
  const int yb = blockIdx.y * TH;
  const int base = wid * 8;

  const float m0 = (float)(acc[0] / (double)NHW);
  const float cad0 = fmaxf(cadc[0], 0.f);
  const float cad1 = fmaxf(cadc[1], 0.f);
  const float cad2 = fmaxf(cadc[2], 0.f);
  const float my0 = fmaxf(myoc[0], 0.f);
  const float my1 = fmaxf(myoc[1], 0.f);
  const float my2 = fmaxf(myoc[2], 0.f);
  const float my3 = fmaxf(myoc[3], 0.f);
  const float my4 = fmaxf(myoc[4], 0.f);

// Wave `wid` stages tile rows wid, wid+8, ..., wid+96 (13 rows).
#define SGLD(sp, k) \
  (sp)[(size_t)(((yb - RAD + wid + 8 * (k)) + NH) & (NH - 1)) * NW + x0 + lane]

  float u0, u1, u2, u3, u4, u5, u6;
  float u7, u8, u9, u10, u11, u12;

#define LOADCH(srcp)                                                   \
  {                                                                    \
    const float* sp_ = (srcp);                                         \
    u0 = SGLD(sp_, 0); u1 = SGLD(sp_, 1); u2 = SGLD(sp_, 2);           \
    u3 = SGLD(sp_, 3); u4 = SGLD(sp_, 4); u5 = SGLD(sp_, 5);           \
    u6 = SGLD(sp_, 6); u7 = SGLD(sp_, 7); u8 = SGLD(sp_, 8);           \
    u9 = SGLD(sp_, 9); u10 = SGLD(sp_, 10); u11 = SGLD(sp_, 11);       \
    u12 = SGLD(sp_, 12);                                               \
  }
#define WRITECH(g)                                                        \
  {                                                                       \
    float* tb_ = &tile[(g) * TILE_CH];                                    \
    tb_[(wid + 0) * TW + lane] = u0;   tb_[(wid + 8) * TW + lane] = u1;   \
    tb_[(wid + 16) * TW + lane] = u2;  tb_[(wid + 24) * TW + lane] = u3;  \
    tb_[(wid + 32) * TW + lane] = u4;  tb_[(wid + 40) * TW + lane] = u5;  \
    tb_[(wid + 48) * TW + lane] = u6;  tb_[(wid + 56) * TW + lane] = u7;  \
    tb_[(wid + 64) * TW + lane] = u8;  tb_[(wid + 72) * TW + lane] = u9;  \
    tb_[(wid + 80) * TW + lane] = u10; tb_[(wid + 88) * TW + lane] = u11; \
    tb_[(wid + 96) * TW + lane] = u12;                                    \
  }
#define DECL8(P)                                                       \
  float P##0 = 0.f, P##1 = 0.f, P##2 = 0.f, P##3 = 0.f, P##4 = 0.f,    \
        P##5 = 0.f, P##6 = 0.f, P##7 = 0.f;
#define CALLCONV(g, P)                                                  \
  conv_col(&tile[(g) * TILE_CH], base, lane, P##0, P##1, P##2, P##3,    \
           P##4, P##5, P##6, P##7);

  DECL8(ym00) DECL8(ym01) DECL8(ym10) DECL8(ym11)
  DECL8(yc) DECL8(yv0) DECL8(yv1)

  // Prologue: stage ch0 (m00) into slot 0.
  LOADCH(y)
  WRITECH(0)
  __syncthreads();
  // Step 0: conv m00 (slot0); prefetch+write m01 -> slot1.
  LOADCH(y + (size_t)NHW)
  CALLCONV(0, ym00)
  WRITECH(1)
  __syncthreads();
  // Step 1: conv m01 (slot1); prefetch+write m10 -> slot0.
  LOADCH(y + 2 * (size_t)NHW)
  CALLCONV(1, ym01)
  WRITECH(0)
  __syncthreads();
  // Step 2: conv m10 (slot0); prefetch+write m11 -> slot1.
  LOADCH(y + 3 * (size_t)NHW)
  CALLCONV(0, ym10)
  WRITECH(1)
  __syncthreads();
  // Step 3: conv m11 (slot1); prefetch+write c -> slot0.
  LOADCH(y + 4 * (size_t)NHW)
  CALLCONV(1, ym11)
  WRITECH(0)
  __syncthreads();
  // Step 4: conv c (slot0); prefetch+write v0 -> slot1.
  LOADCH(v)
  CALLCONV(0, yc)
  WRITECH(1)
  __syncthreads();
  // Step 5: conv v0 (slot1); prefetch+write v1 -> slot0.
  LOADCH(v + (size_t)NHW)
  CALLCONV(1, yv0)
  WRITECH(0)
  __syncthreads();
  // Step 6: conv v1 (slot0). No further staging, no barrier needed.
  CALLCONV(0, yv1)

  // Phase C: pointwise algebra per owned pixel (rows yb+base+q, col x0+lane).
  // m/c/v re-read from global: L2-hot (this block staged them just now).
#define POINT(q)                                                              \
  {                                                                           \
    const size_t idx = (size_t)(yb + base + (q)) * NW + x0 + lane;            \
    const float m00 = y[idx];                                                 \
    const float m01 = y[idx + (size_t)NHW];                                   \
    const float m10 = y[idx + 2 * (size_t)NHW];                               \
    const float m11 = y[idx + 3 * (size_t)NHW];                               \
    const float c = y[idx + 4 * (size_t)NHW];                                 \
    const float v0 = v[idx];                                                  \
    const float v1 = v[idx + (size_t)NHW];                                    \
    const float g = gds[idx];                                                 \
    const float dY_m00 = ym00##q, dY_m01 = ym01##q;                           \
    const float dY_m10 = ym10##q, dY_m11 = ym11##q;                           \
    const float dY_c = yc##q, dY_v0 = yv0##q, dY_v1 = yv1##q;                 \
    const float dX_m00 = ws[idx + 7 * (size_t)NHW];                           \
    const float dX_m01 = ws[idx + 8 * (size_t)NHW];                           \
    const float dX_m10 = ws[idx + 9 * (size_t)NHW];                           \
    const float dX_m11 = ws[idx + 10 * (size_t)NHW];                          \
    const float dX_c = ws[idx + 11 * (size_t)NHW];                            \
    const float dX_v0 = ws[idx + 12 * (size_t)NHW];                           \
    const float dX_v1 = ws[idx + 13 * (size_t)NHW];                           \
    const float gv00 = dY_v0, gv01 = dX_v0, gv10 = dY_v1, gv11 = dX_v1;       \
    const float ww = -0.5f * (gv01 - gv10);                                   \
    const float E00 = gv00, E11 = gv11;                                       \
    const float E01 = 0.5f * (gv01 + gv10);                                   \
    const float E10 = E01;                                                    \
    const float trm = m00 + m11;                                              \
    const float dev00 = m00 - 0.5f * trm;                                     \
    const float dev01 = m01;                                                  \
    const float dev10 = m10;                                                  \
    const float dev11 = m11 - 0.5f * trm;                                     \
    const float dmag_sq =                                                     \
        dev00 * dev00 + dev01 * dev01 + dev10 * dev10 + dev11 * dev11;        \
    const float dm = sqrtf(dmag_sq);                                          \
    const float dm2 = dm * dm;                                                \
    const float devE = dev00 * E00 + dev01 * E01 + dev10 * E10 + dev11 * E11; \
    const float sg = (devE > 0.f) ? 1.f : ((devE < 0.f) ? -1.f : 0.f);        \
    const float coef = sg * devE / dm2;                                       \
    const float sc = 0.5f * dm / m0;                                          \
    const float Ea00 = (E00 - coef * dev00) * sc;                             \
    const float Ea01 = (E01 - coef * dev01) * sc;                             \
    const float Ea10 = (E10 - coef * dev10) * sc;                             \
    const float Ea11 = (E11 - coef * dev11) * sc;                             \
    const float Ep00 = E00 - Ea00;                                            \
    const float Ep01 = E01 - Ea01;                                            \
    const float Ep10 = E10 - Ea10;                                            \
    const float Ep11 = E11 - Ea11;                                            \
    const float mE00 = (m00 * Ep00 + m01 * Ep10) + (Ep00 * m00 + Ep01 * m10); \
    const float mE01 = (m00 * Ep01 + m01 * Ep11) + (Ep00 * m01 + Ep01 * m11); \
    const float mE10 = (m10 * Ep00 + m11 * Ep10) + (Ep10 * m00 + Ep11 * m10); \
    const float mE11 = (m10 * Ep01 + m11 * Ep11) + (Ep10 * m01 + Ep11 * m11); \
    const float divv = gv00 + gv11;                                           \
    const float cdot =                                                        \
        -(v0 * dY_c + v1 * dX_c) - cad0 * c + cad1 * c * divv + cad2 * g;     \
    const float md00 = -(v0 * dY_m00 + v1 * dX_m00) - ww * m10 - ww * m01 -   \
                       my0 * m00 + my1 * mE00 - my2 * c * mE00 + my3 * trm +  \
                       my4 * trm * m00;                                       \
    const float md01 = -(v0 * dY_m01 + v1 * dX_m01) - ww * m11 + ww * m00 -   \
                       my0 * m01 + my1 * mE01 - my2 * c * mE01 +              \
                       my4 * trm * m01;                                       \
    const float md10 = -(v0 * dY_m10 + v1 * dX_m10) + ww * m00 - ww * m11 -   \
                       my0 * m10 + my1 * mE10 - my2 * c * mE10 +              \
                       my4 * trm * m10;                                       \
    const float md11 = -(v0 * dY_m11 + v1 * dX_m11) + ww * m01 + ww * m10 -   \
                       my0 * m11 + my1 * mE11 - my2 * c * mE11 +              \
                       my4 * trm * m11;                                       \
    out[idx] = md00;                                                          \
    out[idx + (size_t)NHW] = md01;                                            \
    out[idx + 2 * (size_t)NHW] = md10;                                        \
    out[idx + 3 * (size_t)NHW] = md11;                                        \
    out[idx + 4 * (size_t)NHW] = cdot;                                        \
  }

  POINT(0) POINT(1) POINT(2) POINT(3)
  POINT(4) POINT(5) POINT(6) POINT(7)
#undef POINT
}

extern "C" void kernel_launch(void* const* d_in, const int* in_sizes, int n_in,
                              void* d_out, int out_size, void* d_ws, size_t ws_size,
                              hipStream_t stream) {
  (void)in_sizes; (void)n_in; (void)out_size; (void)ws_size;
  const float* y = (const float*)d_in[0];
  const float* v = (const float*)d_in[1];
  const float* gds = (const float*)d_in[2];
  const float* cadc = (const float*)d_in[3];
  const float* myoc = (const float*)d_in[4];
  float* out = (float*)d_out;

  double* acc = (double*)d_ws;                       // 8B accumulator
  float* planes = (float*)((char*)d_ws + 512);       // 14 x NHW fp32 planes (7..13 used)

  hipMemsetAsync(acc, 0, sizeof(double), stream);
  k_dx<<<dim3(NH / 4, 7), dim3(256), 0, stream>>>(y, v, planes, acc);
  k_dyf<<<dim3(NW / TW, NH / TH), dim3(512), 0, stream>>>(y, v, gds, cadc, myoc,
                                                          planes, acc, out);
}